// Round 1
// baseline (598.388 us; speedup 1.0000x reference)
//
#include <hip/hip_runtime.h>
#include <math.h>

#define BB 512
#define LL 1024
#define EMB 4
#define CC 64
#define NTF 200
#define TT 247      // seq len after conv1
#define LP 254      // after pool
#define D2 128

typedef __attribute__((ext_vector_type(8))) short short8;
typedef __attribute__((ext_vector_type(4))) float f32x4;
typedef __attribute__((ext_vector_type(4))) unsigned int uint4v;

#define L2E  1.4426950408889634f   // log2(e)
#define TL2E 2.8853900817779268f   // 2*log2(e)

// Fast nonlinearities: v_rcp_f32 (1 ulp) instead of IEEE division chain.
__device__ __forceinline__ float sigf(float x) {
  return __builtin_amdgcn_rcpf(1.0f + __expf(-x));
}
__device__ __forceinline__ float tanhff(float x) {
  return 1.0f - 2.0f * __builtin_amdgcn_rcpf(__expf(2.0f * x) + 1.0f);
}

// exp2 native (v_exp_f32 computes 2^x)
__device__ __forceinline__ float ex2(float x) {
#if defined(__has_builtin)
#if __has_builtin(__builtin_amdgcn_exp2f)
  return __builtin_amdgcn_exp2f(x);
#else
  return exp2f(x);
#endif
#else
  return exp2f(x);
#endif
}
// y is the preactivation already scaled by log2(e)
__device__ __forceinline__ float sig2(float y) {
  return __builtin_amdgcn_rcpf(1.0f + ex2(-y));
}
// y is the preactivation already scaled by 2*log2(e)
__device__ __forceinline__ float tanh2(float y) {
  return 1.0f - 2.0f * __builtin_amdgcn_rcpf(ex2(y) + 1.0f);
}

// LDS-only barrier: 0xC07F = vmcnt(63)|expcnt(7)|lgkmcnt(0).
__device__ __forceinline__ void lds_barrier() {
  __builtin_amdgcn_s_waitcnt(0xC07F);
  __builtin_amdgcn_s_barrier();
}

// f32 -> bf16 round-to-nearest-even (finite inputs)
__device__ __forceinline__ unsigned short bfr(float f) {
  unsigned u = __builtin_bit_cast(unsigned, f);
  u += 0x7fffu + ((u >> 16) & 1u);
  return (unsigned short)(u >> 16);
}

// ---------------- K0: weight conversions ----------------
// grid 6400*256 covers fc1w (1,638,400). wbf1r is w1 REORDERED to [co][k][ci].
// LSTM gate weights/biases are PRE-SCALED by log2(e) (2*log2e for g gate) so the
// sequential kernel can use native exp2 without per-element range scaling.
__global__ __launch_bounds__(256) void k_cvt(const float* __restrict__ w0,
    const float* __restrict__ w1,
    const float* __restrict__ wihf, const float* __restrict__ whhf,
    const float* __restrict__ wihb, const float* __restrict__ whhb,
    const float* __restrict__ bihf, const float* __restrict__ bhhf,
    const float* __restrict__ bihb, const float* __restrict__ bhhb,
    const float* __restrict__ W1w, const float* __restrict__ Vw,
    const float* __restrict__ f1w,
    unsigned short* __restrict__ wbf0, unsigned short* __restrict__ wbf1r,
    unsigned short* __restrict__ wihbf, unsigned short* __restrict__ whhbf,
    float* __restrict__ lbias,
    unsigned short* __restrict__ W1bf, unsigned short* __restrict__ Vbf,
    unsigned short* __restrict__ f1bf)
{
  int i = blockIdx.x * 256 + threadIdx.x;
  if (i < 2048) wbf0[i] = bfr(w0[i]);
  if (i < 32768) {                           // dst [co][k][ci] <- src [co][ci][k]
    int co = i >> 9, k = (i >> 6) & 7, ci = i & 63;
    wbf1r[i] = bfr(w1[co * 512 + ci * 8 + k]);
  }
  if (i < 16384) {
    float s = ((i >> 12) == 2) ? TL2E : L2E;  // gate = row>>6 = i>>12
    wihbf[i] = bfr(wihf[i] * s);
    wihbf[16384 + i] = bfr(wihb[i] * s);
    whhbf[i] = bfr(whhf[i] * s);
    whhbf[16384 + i] = bfr(whhb[i] * s);
    W1bf[i] = bfr(W1w[i]);                    // attention W1: unscaled
  }
  if (i < 26624) {                           // Vbf padded to 208 rows
    int row = i >> 7;
    Vbf[i] = (row < NTF) ? bfr(Vw[i]) : (unsigned short)0;
  }
  if (i < 256) {
    float s = ((i >> 6) == 2) ? TL2E : L2E;
    lbias[i] = (bihf[i] + bhhf[i]) * s;
    lbias[256 + i] = (bihb[i] + bhhb[i]) * s;
  }
  if (i < 1638400) f1bf[i] = bfr(f1w[i]);    // [n][o][k] flat
}

// ---------------- K1: conv0 + BN + ReLU + maxpool(4), MFMA -> pbf (bf16) ----------------
__global__ __launch_bounds__(256) void k_conv0m(const float* __restrict__ x,
    const unsigned short* __restrict__ wbf0,
    const float* __restrict__ b0, const float* __restrict__ g0,
    const float* __restrict__ be0, const float* __restrict__ m0,
    const float* __restrict__ v0, unsigned short* __restrict__ pbf)
{
  int b = blockIdx.x, l0 = blockIdx.y * 64;
  __shared__ float xs[71 * 4];
  __shared__ float sc[64], sb[64];
  int tid = threadIdx.x;
  for (int j = tid; j < 71; j += 256) {
    int l = l0 + j;
    float4 xv = (l < LL) ? *(const float4*)(x + ((size_t)b * LL + l) * EMB)
                         : make_float4(0.f, 0.f, 0.f, 0.f);
    *(float4*)(xs + j * 4) = xv;
  }
  if (tid < 64) {
    float s = g0[tid] * rsqrtf(v0[tid] + 1e-5f);
    sc[tid] = s;
    sb[tid] = (b0[tid] - m0[tid]) * s + be0[tid];
  }
  __syncthreads();
  int w = tid >> 6, lane = tid & 63, nl = lane & 15, quad = lane >> 4;
  const float* ap = xs + (w * 16 + nl) * 4 + quad;
  short8 af;
  #pragma unroll
  for (int j = 0; j < 8; ++j) af[j] = (short)bfr(ap[j * 4]);
  f32x4 acc[4];
  #pragma unroll
  for (int nt = 0; nt < 4; ++nt) {
    short8 bf = __builtin_bit_cast(short8,
        *(const uint4v*)(wbf0 + ((nt * 16 + nl) * 32 + quad * 8)));
    acc[nt] = (f32x4){0.f, 0.f, 0.f, 0.f};
    acc[nt] = __builtin_amdgcn_mfma_f32_16x16x32_bf16(af, bf, acc[nt], 0, 0, 0);
  }
  int t = (l0 >> 2) + w * 4 + quad;
  if (t < LP) {
    #pragma unroll
    for (int nt = 0; nt < 4; ++nt) {
      int c = nt * 16 + nl;
      float scc = sc[c], sbc = sb[c];
      float mx = -1e30f;
      #pragma unroll
      for (int r = 0; r < 4; ++r) mx = fmaxf(mx, acc[nt][r] * scc + sbc);
      pbf[((size_t)b * LP + t) * CC + c] = bfr(fmaxf(mx, 0.0f));
    }
  }
}

// ---------------- K2: conv1 as 8 shifted GEMMs (bf16 p, reordered weights) ----------------
__global__ __launch_bounds__(256) void k_conv1m(const unsigned short* __restrict__ pbf,
    const unsigned short* __restrict__ wbf1r,
    const float* __restrict__ b1, const float* __restrict__ g1,
    const float* __restrict__ be1, const float* __restrict__ m1,
    const float* __restrict__ v1, unsigned short* __restrict__ x2bf)
{
  int b = blockIdx.x, t0 = blockIdx.y * 64;
  __shared__ __align__(16) unsigned short ps[71 * 72];
  __shared__ float sc[64], sb[64];
  int tid = threadIdx.x;
  for (int j = tid; j < 71 * 32; j += 256) {
    int tl = j >> 5, cu = j & 31;
    int t = t0 + tl;
    unsigned v = (t < LP) ? *(const unsigned*)(pbf + ((size_t)b * LP + t) * CC + cu * 2) : 0u;
    *(unsigned*)(&ps[tl * 72 + cu * 2]) = v;
  }
  if (tid < 64) {
    float s = g1[tid] * rsqrtf(v1[tid] + 1e-5f);
    sc[tid] = s;
    sb[tid] = (b1[tid] - m1[tid]) * s + be1[tid];
  }
  __syncthreads();
  int w = tid >> 6, lane = tid & 63, nl = lane & 15, quad = lane >> 4;
  int tlb = w * 16 + nl;
  f32x4 acc[4];
  #pragma unroll
  for (int nt = 0; nt < 4; ++nt) acc[nt] = (f32x4){0.f, 0.f, 0.f, 0.f};
  #pragma unroll
  for (int k8 = 0; k8 < 8; ++k8) {
    short8 af0 = __builtin_bit_cast(short8,
        *(const uint4v*)(&ps[(tlb + k8) * 72 + 0 + quad * 8]));
    short8 af1 = __builtin_bit_cast(short8,
        *(const uint4v*)(&ps[(tlb + k8) * 72 + 32 + quad * 8]));
    #pragma unroll
    for (int nt = 0; nt < 4; ++nt) {
      int co = nt * 16 + nl;
      short8 bf0 = __builtin_bit_cast(short8,
          *(const uint4v*)(wbf1r + (size_t)co * 512 + k8 * 64 + 0 + quad * 8));
      short8 bf1 = __builtin_bit_cast(short8,
          *(const uint4v*)(wbf1r + (size_t)co * 512 + k8 * 64 + 32 + quad * 8));
      acc[nt] = __builtin_amdgcn_mfma_f32_16x16x32_bf16(af0, bf0, acc[nt], 0, 0, 0);
      acc[nt] = __builtin_amdgcn_mfma_f32_16x16x32_bf16(af1, bf1, acc[nt], 0, 0, 0);
    }
  }
  #pragma unroll
  for (int nt = 0; nt < 4; ++nt) {
    int c = nt * 16 + nl;
    float scc = sc[c], sbc = sb[c];
    #pragma unroll
    for (int r = 0; r < 4; ++r) {
      int t = t0 + w * 16 + quad * 4 + r;
      if (t < TT)
        x2bf[((size_t)b * TT + t) * CC + c] = bfr(fmaxf(acc[nt][r] * scc + sbc, 0.0f));
    }
  }
}

// ---------------- K3: bi-LSTM via MFMA, 2 interleaved chains per block ----------------
// 32 blocks x 256 thr: each block runs TWO independent batch-tiles (same dir) so
// chain B's MFMAs/exp-chains fill chain A's latency stalls (1 wave/SIMD otherwise).
// x A-frags come straight from global (prefetched 1 step ahead) -- no xls staging.
// Gate weights pre-scaled by log2e (2*log2e for g) -> native exp2 nonlinearities.
__global__ __launch_bounds__(256) void k_lstm_m(const unsigned short* __restrict__ x2bf,
    const unsigned short* __restrict__ wihbf, const unsigned short* __restrict__ whhbf,
    const float* __restrict__ lbias,
    unsigned short* __restrict__ values, float* __restrict__ hT)
{
  int dir = blockIdx.y;
  int b0A = blockIdx.x * 32, b0B = b0A + 16;
  int tid = threadIdx.x;
  int w = tid >> 6, lane = tid & 63, l15 = lane & 15, quad = lane >> 4;
  int h0 = w * 16;
  const unsigned short* wih = wihbf + dir * 16384;
  const unsigned short* whh = whhbf + dir * 16384;

  short8 bx[4][2], bh[4][2];
  float bias_v[4];
  #pragma unroll
  for (int g = 0; g < 4; ++g) {
    int row = g * 64 + h0 + l15;
    #pragma unroll
    for (int k = 0; k < 2; ++k) {
      bx[g][k] = __builtin_bit_cast(short8, *(const uint4v*)(wih + row * 64 + k * 32 + quad * 8));
      bh[g][k] = __builtin_bit_cast(short8, *(const uint4v*)(whh + row * 64 + k * 32 + quad * 8));
    }
    bias_v[g] = lbias[dir * 256 + g * 64 + h0 + l15];
  }

  __shared__ __align__(16) unsigned short histA[8][16 * 72];
  __shared__ __align__(16) unsigned short histB[8][16 * 72];
  for (int j = tid; j < 16 * 72; j += 256) { histA[7][j] = 0; histB[7][j] = 0; }
  __syncthreads();

  // per-lane x base: A-frag row = batch l15, k = quad*8 (+32 for upper half)
  const unsigned short* xA = x2bf + ((size_t)(b0A + l15) * TT) * 64 + quad * 8;
  const unsigned short* xB = x2bf + ((size_t)(b0B + l15) * TT) * 64 + quad * 8;

  uint4v xra[2][2], xrb[2][2];   // [parity][half], parity static via unrolled sl
  {
    size_t o0 = (size_t)(dir ? (TT - 1) : 0) * 64;
    xra[0][0] = *(const uint4v*)(xA + o0);
    xra[0][1] = *(const uint4v*)(xA + o0 + 32);
    xrb[0][0] = *(const uint4v*)(xB + o0);
    xrb[0][1] = *(const uint4v*)(xB + o0 + 32);
  }

  float cA[4] = {0.f, 0.f, 0.f, 0.f}, cB[4] = {0.f, 0.f, 0.f, 0.f};

  for (int c = 0; c < 31; ++c) {
    #pragma unroll
    for (int sl = 0; sl < 8; ++sl) {
      int s = c * 8 + sl;
      const int par = sl & 1;
      if (s < TT) {
        int hp = (sl + 7) & 7;
        short8 ahA0 = __builtin_bit_cast(short8, *(const uint4v*)(&histA[hp][l15 * 72 + quad * 8]));
        short8 ahA1 = __builtin_bit_cast(short8, *(const uint4v*)(&histA[hp][l15 * 72 + 32 + quad * 8]));
        short8 ahB0 = __builtin_bit_cast(short8, *(const uint4v*)(&histB[hp][l15 * 72 + quad * 8]));
        short8 ahB1 = __builtin_bit_cast(short8, *(const uint4v*)(&histB[hp][l15 * 72 + 32 + quad * 8]));
        short8 axA0 = __builtin_bit_cast(short8, xra[par][0]);
        short8 axA1 = __builtin_bit_cast(short8, xra[par][1]);
        short8 axB0 = __builtin_bit_cast(short8, xrb[par][0]);
        short8 axB1 = __builtin_bit_cast(short8, xrb[par][1]);
        {   // prefetch next step's x frags (latency hides under this round)
          int sn = s + 1; if (sn > TT - 1) sn = TT - 1;
          size_t on = (size_t)(dir ? (TT - 1 - sn) : sn) * 64;
          xra[par ^ 1][0] = *(const uint4v*)(xA + on);
          xra[par ^ 1][1] = *(const uint4v*)(xA + on + 32);
          xrb[par ^ 1][0] = *(const uint4v*)(xB + on);
          xrb[par ^ 1][1] = *(const uint4v*)(xB + on + 32);
        }
        f32x4 aA[4], aB[4];
        #pragma unroll
        for (int g = 0; g < 4; ++g) {
          aA[g] = (f32x4){bias_v[g], bias_v[g], bias_v[g], bias_v[g]};
          aA[g] = __builtin_amdgcn_mfma_f32_16x16x32_bf16(axA0, bx[g][0], aA[g], 0, 0, 0);
          aA[g] = __builtin_amdgcn_mfma_f32_16x16x32_bf16(axA1, bx[g][1], aA[g], 0, 0, 0);
          aA[g] = __builtin_amdgcn_mfma_f32_16x16x32_bf16(ahA0, bh[g][0], aA[g], 0, 0, 0);
          aA[g] = __builtin_amdgcn_mfma_f32_16x16x32_bf16(ahA1, bh[g][1], aA[g], 0, 0, 0);
          aB[g] = (f32x4){bias_v[g], bias_v[g], bias_v[g], bias_v[g]};
          aB[g] = __builtin_amdgcn_mfma_f32_16x16x32_bf16(axB0, bx[g][0], aB[g], 0, 0, 0);
          aB[g] = __builtin_amdgcn_mfma_f32_16x16x32_bf16(axB1, bx[g][1], aB[g], 0, 0, 0);
          aB[g] = __builtin_amdgcn_mfma_f32_16x16x32_bf16(ahB0, bh[g][0], aB[g], 0, 0, 0);
          aB[g] = __builtin_amdgcn_mfma_f32_16x16x32_bf16(ahB1, bh[g][1], aB[g], 0, 0, 0);
        }
        #pragma unroll
        for (int r = 0; r < 4; ++r) {
          int hw = (quad * 4 + r) * 72 + h0 + l15;
          {
            float ig = sig2(aA[0][r]);
            float fg = sig2(aA[1][r]);
            float gg = tanh2(aA[2][r]);
            float og = sig2(aA[3][r]);
            cA[r] = fg * cA[r] + ig * gg;
            float hh = og * tanh2(cA[r] * TL2E);
            histA[sl][hw] = bfr(hh);
            if (s == TT - 1)
              hT[((size_t)dir * BB + (b0A + quad * 4 + r)) * 64 + h0 + l15] = hh;
          }
          {
            float ig = sig2(aB[0][r]);
            float fg = sig2(aB[1][r]);
            float gg = tanh2(aB[2][r]);
            float og = sig2(aB[3][r]);
            cB[r] = fg * cB[r] + ig * gg;
            float hh = og * tanh2(cB[r] * TL2E);
            histB[sl][hw] = bfr(hh);
            if (s == TT - 1)
              hT[((size_t)dir * BB + (b0B + quad * 4 + r)) * 64 + h0 + l15] = hh;
          }
        }
      }
      lds_barrier();
    }
    // store values for this chunk (both chains); vmcnt not waited at lds_barrier
    #pragma unroll
    for (int i = 0; i < 4; ++i) {
      int flat = i * 256 + tid;
      int sl2 = flat >> 7, wb = (flat >> 3) & 15, c8 = flat & 7;
      int s = c * 8 + sl2;
      if (s < TT) {
        uint4v dvA = *(const uint4v*)(&histA[sl2][wb * 72 + c8 * 8]);
        uint4v dvB = *(const uint4v*)(&histB[sl2][wb * 72 + c8 * 8]);
        int t = dir ? (TT - 1 - s) : s;
        *(uint4v*)(values + ((size_t)(b0A + wb) * TT + t) * D2 + dir * 64 + c8 * 8) = dvA;
        *(uint4v*)(values + ((size_t)(b0B + wb) * TT + t) * D2 + dir * 64 + c8 * 8) = dvB;
      }
    }
    lds_barrier();   // protect hist[0] overwrite in next chunk
  }
}

// ---------------- K3b: q2 = h_n @ W2^T + W2_b ----------------
__global__ __launch_bounds__(128) void k_q2(const float* __restrict__ hT,
    const float* __restrict__ W2, const float* __restrict__ W2b,
    float* __restrict__ q2)
{
  int b = blockIdx.x;
  int tid = threadIdx.x;
  __shared__ float4 hn4[32];
  ((float*)hn4)[tid] = hT[(size_t)b * 128 + tid];
  __syncthreads();
  const float4* w4 = (const float4*)(W2 + (size_t)tid * 128);
  float a = W2b[tid];
  #pragma unroll
  for (int j = 0; j < 32; ++j) {
    float4 w = w4[j]; float4 h = hn4[j];
    a += w.x * h.x + w.y * h.y + w.z * h.z + w.w * h.w;
  }
  q2[(size_t)b * 128 + tid] = a;
}

// ---------------- K4: score via MFMA -> scoreT[b][n][t] bf16 ----------------
__global__ __launch_bounds__(256) void k_score_m(const unsigned short* __restrict__ vbf,
    const unsigned short* __restrict__ W1bf, const float* __restrict__ W1b,
    const float* __restrict__ q2, const unsigned short* __restrict__ Vbf,
    const float* __restrict__ Vb, unsigned short* __restrict__ scoreT)
{
  int b = blockIdx.x, t0 = blockIdx.y * 64;
  int tid = threadIdx.x, w = tid >> 6, lane = tid & 63, l15 = lane & 15, quad = lane >> 4;
  __shared__ unsigned short us[64 * 136];
  __shared__ unsigned short sc2[64 * 213];
  const unsigned short* arow = vbf + ((size_t)b * TT + t0 + w * 16 + l15) * 128;
  short8 ax[4];
  #pragma unroll
  for (int ks = 0; ks < 4; ++ks)
    ax[ks] = __builtin_bit_cast(short8, *(const uint4v*)(arow + ks * 32 + quad * 8));
  #pragma unroll
  for (int nt = 0; nt < 8; ++nt) {
    int n = nt * 16 + l15;
    float base = W1b[n] + q2[(size_t)b * 128 + n];
    f32x4 acc = (f32x4){base, base, base, base};
    #pragma unroll
    for (int ks = 0; ks < 4; ++ks) {
      short8 bf = __builtin_bit_cast(short8,
          *(const uint4v*)(W1bf + (size_t)n * 128 + ks * 32 + quad * 8));
      acc = __builtin_amdgcn_mfma_f32_16x16x32_bf16(ax[ks], bf, acc, 0, 0, 0);
    }
    #pragma unroll
    for (int r = 0; r < 4; ++r)
      us[(w * 16 + quad * 4 + r) * 136 + nt * 16 + l15] = bfr(tanhff(acc[r]));
  }
  __syncthreads();
  short8 au[4];
  #pragma unroll
  for (int ks = 0; ks < 4; ++ks)
    au[ks] = __builtin_bit_cast(short8, *(const uint4v*)(&us[(w * 16 + l15) * 136 + ks * 32 + quad * 8]));
  for (int nt2 = 0; nt2 < 13; ++nt2) {
    int n = nt2 * 16 + l15;
    float b2 = (n < NTF) ? Vb[n] : 0.0f;
    f32x4 a2 = (f32x4){b2, b2, b2, b2};
    #pragma unroll
    for (int ks = 0; ks < 4; ++ks) {
      short8 bf = __builtin_bit_cast(short8,
          *(const uint4v*)(Vbf + (size_t)n * 128 + ks * 32 + quad * 8));
      a2 = __builtin_amdgcn_mfma_f32_16x16x32_bf16(au[ks], bf, a2, 0, 0, 0);
    }
    #pragma unroll
    for (int r = 0; r < 4; ++r) {
      int tl = w * 16 + quad * 4 + r;
      sc2[tl * 213 + n] = bfr(a2[r]);
    }
  }
  __syncthreads();
  int tg = tid & 3;
  #pragma unroll
  for (int pp = 0; pp < 4; ++pp) {
    int nrow = pp * 64 + (tid >> 2);
    if (nrow < NTF) {
      unsigned uu[8];
      #pragma unroll
      for (int k2 = 0; k2 < 8; ++k2) {
        unsigned lo = sc2[(tg * 16 + k2 * 2) * 213 + nrow];
        unsigned hi = sc2[(tg * 16 + k2 * 2 + 1) * 213 + nrow];
        uu[k2] = lo | (hi << 16);
      }
      size_t dst = ((size_t)b * 208 + nrow) * 256 + t0 + tg * 16;
      *(uint4v*)(scoreT + dst) = (uint4v){uu[0], uu[1], uu[2], uu[3]};
      *(uint4v*)(scoreT + dst + 8) = (uint4v){uu[4], uu[5], uu[6], uu[7]};
    }
  }
}

// ---------------- K5: softmax over t, row-wise on scoreT ----------------
__global__ __launch_bounds__(256) void k_softmax(unsigned short* __restrict__ scoreT,
    float* __restrict__ sinv)
{
  int b = blockIdx.x, nc = blockIdx.y;
  int tid = threadIdx.x;
  int n = nc * 64 + (tid >> 2), tg = tid & 3;
  if (n >= NTF) return;
  unsigned short* row = scoreT + ((size_t)b * 208 + n) * 256 + tg * 64;
  uint4v ld[8];
  #pragma unroll
  for (int i = 0; i < 8; ++i) ld[i] = *(const uint4v*)(row + i * 8);
  float m = -1e30f;
  #pragma unroll
  for (int i = 0; i < 8; ++i) {
    #pragma unroll
    for (int u = 0; u < 4; ++u) {
      unsigned xv = ld[i][u];
      int t0 = tg * 64 + i * 8 + u * 2;
      float a = __builtin_bit_cast(float, xv << 16);
      float c = __builtin_bit_cast(float, xv & 0xffff0000u);
      if (t0 < TT) m = fmaxf(m, a);
      if (t0 + 1 < TT) m = fmaxf(m, c);
    }
  }
  m = fmaxf(m, __shfl_xor(m, 1, 64));
  m = fmaxf(m, __shfl_xor(m, 2, 64));
  float s = 0.0f;
  #pragma unroll
  for (int i = 0; i < 8; ++i) {
    uint4v ov;
    #pragma unroll
    for (int u = 0; u < 4; ++u) {
      unsigned xv = ld[i][u];
      int t0 = tg * 64 + i * 8 + u * 2;
      float a = __builtin_bit_cast(float, xv << 16);
      float c = __builtin_bit_cast(float, xv & 0xffff0000u);
      float ea = (t0 < TT) ? __expf(a - m) : 0.0f;
      float ec = (t0 + 1 < TT) ? __expf(c - m) : 0.0f;
      s += ea + ec;
      ov[u] = (unsigned)bfr(ea) | ((unsigned)bfr(ec) << 16);
    }
    *(uint4v*)(row + i * 8) = ov;
  }
  s += __shfl_xor(s, 1, 64);
  s += __shfl_xor(s, 2, 64);
  if (tg == 0) sinv[(size_t)b * NTF + n] = __builtin_amdgcn_rcpf(s);
}

// ---------------- K6: context via MFMA -> ctxbf (bf16) ----------------
__global__ __launch_bounds__(256) void k_ctx_m(const unsigned short* __restrict__ vbf,
    const unsigned short* __restrict__ scoreT, const float* __restrict__ sinv,
    unsigned short* __restrict__ ctxbf)
{
  int b = blockIdx.x;
  int tid = threadIdx.x, w = tid >> 6, lane = tid & 63, l15 = lane & 15, quad = lane >> 4;
  __shared__ __align__(16) unsigned short vt[128 * 264];  // [d][t]
  __shared__ float sls[208];
  for (int flat = tid; flat < 247 * 64; flat += 256) {
    int t = flat >> 6, dp = flat & 63;
    unsigned v = *(const unsigned*)(vbf + ((size_t)b * TT + t) * D2 + dp * 2);
    vt[(dp * 2) * 264 + t] = (unsigned short)(v & 0xffffu);
    vt[(dp * 2 + 1) * 264 + t] = (unsigned short)(v >> 16);
  }
  for (int j = tid; j < 128 * 9; j += 256) {
    int d = j / 9, t = 247 + (j % 9);
    vt[d * 264 + t] = 0;
  }
  for (int j = tid; j < 208; j += 256) sls[j] = (j < NTF) ? sinv[(size_t)b * NTF + j] : 0.0f;
  __syncthreads();

  const unsigned short* abase = scoreT + (size_t)b * 208 * 256;
  for (int mi = 0; mi < 4; ++mi) {
    int mt = w + 4 * mi;
    if (mt >= 13) continue;
    const unsigned short* arow = abase + (size_t)(mt * 16 + l15) * 256;
    short8 af[8];
    #pragma unroll
    for (int ks = 0; ks < 8; ++ks)
      af[ks] = __builtin_bit_cast(short8, *(const uint4v*)(arow + ks * 32 + quad * 8));
    f32x4 acc[8];
    #pragma unroll
    for (int dt = 0; dt < 8; ++dt) {
      acc[dt] = (f32x4){0.f, 0.f, 0.f, 0.f};
      #pragma unroll
      for (int ks = 0; ks < 8; ++ks) {
        short8 bf = __builtin_bit_cast(short8,
            *(const uint4v*)(&vt[(dt * 16 + l15) * 264 + ks * 32 + quad * 8]));
        acc[dt] = __builtin_amdgcn_mfma_f32_16x16x32_bf16(af[ks], bf, acc[dt], 0, 0, 0);
      }
    }
    #pragma unroll
    for (int r = 0; r < 4; ++r) {
      int n = mt * 16 + quad * 4 + r;
      if (n < NTF) {
        float rs = sls[n];
        #pragma unroll
        for (int dt = 0; dt < 8; ++dt)
          ctxbf[((size_t)b * NTF + n) * D2 + dt * 16 + l15] = bfr(acc[dt][r] * rs);
      }
    }
  }
}

// ---------------- K7: per-TF heads via MFMA ----------------
// GEMM per n: M=128 batch tile, N=64 (o), K=128; A,B frags direct from global bf16.
__global__ __launch_bounds__(256) void k_heads_m(const unsigned short* __restrict__ ctxbf,
    const unsigned short* __restrict__ f1bf, const float* __restrict__ fc1b,
    const float* __restrict__ fc2w, const float* __restrict__ fc2b,
    float* __restrict__ out)
{
  int n = blockIdx.x;
  int b0 = blockIdx.y * 128;
  int tid = threadIdx.x, w = tid >> 6, lane = tid & 63, l15 = lane & 15, quad = lane >> 4;
  // B-frags: fc1 rows for o = nt*16+l15 (resident)
  short8 bfr_[4][4];
  float f1bv[4], f2v[4];
  #pragma unroll
  for (int nt = 0; nt < 4; ++nt) {
    int o = nt * 16 + l15;
    #pragma unroll
    for (int ks = 0; ks < 4; ++ks)
      bfr_[nt][ks] = __builtin_bit_cast(short8,
          *(const uint4v*)(f1bf + ((size_t)n * 64 + o) * 128 + ks * 32 + quad * 8));
    f1bv[nt] = fc1b[n * 64 + o];
    f2v[nt] = fc2w[n * 64 + o];
  }
  float f2b = fc2b[n];
  #pragma unroll
  for (int mi = 0; mi < 2; ++mi) {
    int m16 = (w * 2 + mi) * 16;
    const unsigned short* arow = ctxbf + ((size_t)(b0 + m16 + l15) * NTF + n) * 128;
    short8 af[4];
    #pragma unroll
    for (int ks = 0; ks < 4; ++ks)
      af[ks] = __builtin_bit_cast(short8, *(const uint4v*)(arow + ks * 32 + quad * 8));
    f32x4 acc[4];
    #pragma unroll
    for (int nt = 0; nt < 4; ++nt) {
      acc[nt] = (f32x4){0.f, 0.f, 0.f, 0.f};
      #pragma unroll
      for (int ks = 0; ks < 4; ++ks)
        acc[nt] = __builtin_amdgcn_mfma_f32_16x16x32_bf16(af[ks], bfr_[nt][ks], acc[nt], 0, 0, 0);
    }
    #pragma unroll
    for (int r = 0; r < 4; ++r) {
      float part = 0.0f;
      #pragma unroll
      for (int nt = 0; nt < 4; ++nt)
        part += fmaxf(acc[nt][r] + f1bv[nt], 0.0f) * f2v[nt];
      part += __shfl_xor(part, 1, 64);
      part += __shfl_xor(part, 2, 64);
      part += __shfl_xor(part, 4, 64);
      part += __shfl_xor(part, 8, 64);
      if (l15 == 0) {
        int bb = b0 + m16 + quad * 4 + r;
        out[(size_t)bb * NTF + n] = part + f2b;
      }
    }
  }
}

extern "C" void kernel_launch(void* const* d_in, const int* in_sizes, int n_in,
                              void* d_out, int out_size, void* d_ws, size_t ws_size,
                              hipStream_t stream)
{
  const float* x    = (const float*)d_in[0];
  const float* c0w  = (const float*)d_in[1];
  const float* c0b  = (const float*)d_in[2];
  const float* g0   = (const float*)d_in[3];
  const float* be0  = (const float*)d_in[4];
  const float* m0   = (const float*)d_in[5];
  const float* v0   = (const float*)d_in[6];
  const float* c1w  = (const float*)d_in[7];
  const float* c1b  = (const float*)d_in[8];
  const float* g1   = (const float*)d_in[9];
  const float* be1  = (const float*)d_in[10];
  const float* m1   = (const float*)d_in[11];
  const float* v1   = (const float*)d_in[12];
  const float* wihf = (const float*)d_in[13];
  const float* whhf = (const float*)d_in[14];
  const float* bihf = (const float*)d_in[15];
  const float* bhhf = (const float*)d_in[16];
  const float* wihb = (const float*)d_in[17];
  const float* whhb = (const float*)d_in[18];
  const float* bihb = (const float*)d_in[19];
  const float* bhhb = (const float*)d_in[20];
  const float* W1w  = (const float*)d_in[21];
  const float* W1b  = (const float*)d_in[22];
  const float* W2w  = (const float*)d_in[23];
  const float* W2b  = (const float*)d_in[24];
  const float* Vw   = (const float*)d_in[25];
  const float* Vb   = (const float*)d_in[26];
  const float* f1w  = (const float*)d_in[27];
  const float* f1b  = (const float*)d_in[28];
  const float* f2w  = (const float*)d_in[29];
  const float* f2b  = (const float*)d_in[30];

  float* ws = (float*)d_ws;
  unsigned short* scoreT = (unsigned short*)ws;            // [b][208][256] bf16
  unsigned short* pbf  = (unsigned short*)ws;              // overlaps scoreT region (dead first)
  unsigned short* x2bf = (unsigned short*)(ws + 8323072);
  unsigned short* vbf  = (unsigned short*)(ws + 25292800);
  float* hT     = ws + 33387520;
  float* q2     = ws + 33453056;
  float* sinv   = ws + 33518592;
  unsigned short* ctxbf = (unsigned short*)(ws + 33620992); // 13.1M shorts
  unsigned short* wbf0  = (unsigned short*)(ws + 46728192);
  unsigned short* wbf1r = (unsigned short*)(ws + 46729216);
  unsigned short* wihbf = (unsigned short*)(ws + 46745600);
  unsigned short* whhbf = (unsigned short*)(ws + 46761984);
  float* lbias          = ws + 46778368;
  unsigned short* W1bf  = (unsigned short*)(ws + 46778880);
  unsigned short* Vbf   = (unsigned short*)(ws + 46787072);
  unsigned short* f1bf  = (unsigned short*)(ws + 46800384); // 1,638,400 shorts
  float* out    = (float*)d_out;

  k_cvt<<<dim3(6400), 256, 0, stream>>>(c0w, c1w, wihf, whhf, wihb, whhb,
                                        bihf, bhhf, bihb, bhhb, W1w, Vw, f1w,
                                        wbf0, wbf1r, wihbf, whhbf, lbias, W1bf, Vbf, f1bf);
  k_conv0m<<<dim3(BB, 16), 256, 0, stream>>>(x, wbf0, c0b, g0, be0, m0, v0, pbf);
  k_conv1m<<<dim3(BB, 4), 256, 0, stream>>>(pbf, wbf1r, c1b, g1, be1, m1, v1, x2bf);
  k_lstm_m<<<dim3(BB / 32, 2), 256, 0, stream>>>(x2bf, wihbf, whhbf, lbias, vbf, hT);
  k_q2<<<dim3(BB), 128, 0, stream>>>(hT, W2w, W2b, q2);
  k_score_m<<<dim3(BB, 4), 256, 0, stream>>>(vbf, W1bf, W1b, q2, Vbf, Vb, scoreT);
  k_softmax<<<dim3(BB, 4), 256, 0, stream>>>(scoreT, sinv);
  k_ctx_m<<<dim3(BB), 256, 0, stream>>>(vbf, scoreT, sinv, ctxbf);
  k_heads_m<<<dim3(NTF, 4), 256, 0, stream>>>(ctxbf, f1bf, f1b, f2w, f2b, out);
}

// Round 2
// 523.685 us; speedup vs baseline: 1.1426x; 1.1426x over previous
//
#include <hip/hip_runtime.h>
#include <math.h>

#define BB 512
#define LL 1024
#define EMB 4
#define CC 64
#define NTF 200
#define TT 247      // seq len after conv1
#define LP 254      // after pool
#define D2 128

typedef __attribute__((ext_vector_type(8))) short short8;
typedef __attribute__((ext_vector_type(4))) float f32x4;
typedef __attribute__((ext_vector_type(4))) unsigned int uint4v;

#define L2E  1.4426950408889634f   // log2(e)
#define TL2E 2.8853900817779268f   // 2*log2(e)

// Fast nonlinearities: v_rcp_f32 (1 ulp) instead of IEEE division chain.
__device__ __forceinline__ float sigf(float x) {
  return __builtin_amdgcn_rcpf(1.0f + __expf(-x));
}
__device__ __forceinline__ float tanhff(float x) {
  return 1.0f - 2.0f * __builtin_amdgcn_rcpf(__expf(2.0f * x) + 1.0f);
}

// exp2 native (v_exp_f32 computes 2^x)
__device__ __forceinline__ float ex2(float x) {
  return __builtin_amdgcn_exp2f(x);
}
// y is the preactivation already scaled by log2(e)
__device__ __forceinline__ float sig2(float y) {
  return __builtin_amdgcn_rcpf(1.0f + ex2(-y));
}
// y is the preactivation already scaled by 2*log2(e)
__device__ __forceinline__ float tanh2(float y) {
  return 1.0f - 2.0f * __builtin_amdgcn_rcpf(ex2(y) + 1.0f);
}

// LDS-only barrier: 0xC07F = vmcnt(63)|expcnt(7)|lgkmcnt(0).
__device__ __forceinline__ void lds_barrier() {
  __builtin_amdgcn_s_waitcnt(0xC07F);
  __builtin_amdgcn_s_barrier();
}

// f32 -> bf16 round-to-nearest-even (finite inputs)
__device__ __forceinline__ unsigned short bfr(float f) {
  unsigned u = __builtin_bit_cast(unsigned, f);
  u += 0x7fffu + ((u >> 16) & 1u);
  return (unsigned short)(u >> 16);
}

// ---------------- K0: weight conversions ----------------
// grid 6400*256 covers fc1w (1,638,400). wbf1r is w1 REORDERED to [co][k][ci].
// LSTM gate weights/biases are PRE-SCALED by log2(e) (2*log2e for g gate) so the
// sequential kernel can use native exp2 without per-element range scaling.
__global__ __launch_bounds__(256) void k_cvt(const float* __restrict__ w0,
    const float* __restrict__ w1,
    const float* __restrict__ wihf, const float* __restrict__ whhf,
    const float* __restrict__ wihb, const float* __restrict__ whhb,
    const float* __restrict__ bihf, const float* __restrict__ bhhf,
    const float* __restrict__ bihb, const float* __restrict__ bhhb,
    const float* __restrict__ W1w, const float* __restrict__ Vw,
    const float* __restrict__ f1w,
    unsigned short* __restrict__ wbf0, unsigned short* __restrict__ wbf1r,
    unsigned short* __restrict__ wihbf, unsigned short* __restrict__ whhbf,
    float* __restrict__ lbias,
    unsigned short* __restrict__ W1bf, unsigned short* __restrict__ Vbf,
    unsigned short* __restrict__ f1bf)
{
  int i = blockIdx.x * 256 + threadIdx.x;
  if (i < 2048) wbf0[i] = bfr(w0[i]);
  if (i < 32768) {                           // dst [co][k][ci] <- src [co][ci][k]
    int co = i >> 9, k = (i >> 6) & 7, ci = i & 63;
    wbf1r[i] = bfr(w1[co * 512 + ci * 8 + k]);
  }
  if (i < 16384) {
    float s = ((i >> 12) == 2) ? TL2E : L2E;  // gate = row>>6 = i>>12
    wihbf[i] = bfr(wihf[i] * s);
    wihbf[16384 + i] = bfr(wihb[i] * s);
    whhbf[i] = bfr(whhf[i] * s);
    whhbf[16384 + i] = bfr(whhb[i] * s);
    W1bf[i] = bfr(W1w[i]);                    // attention W1: unscaled
  }
  if (i < 26624) {                           // Vbf padded to 208 rows
    int row = i >> 7;
    Vbf[i] = (row < NTF) ? bfr(Vw[i]) : (unsigned short)0;
  }
  if (i < 256) {
    float s = ((i >> 6) == 2) ? TL2E : L2E;
    lbias[i] = (bihf[i] + bhhf[i]) * s;
    lbias[256 + i] = (bihb[i] + bhhb[i]) * s;
  }
  if (i < 1638400) f1bf[i] = bfr(f1w[i]);    // [n][o][k] flat
}

// ---------------- K1: conv0 + BN + ReLU + maxpool(4), MFMA -> pbf (bf16) ----------------
__global__ __launch_bounds__(256) void k_conv0m(const float* __restrict__ x,
    const unsigned short* __restrict__ wbf0,
    const float* __restrict__ b0, const float* __restrict__ g0,
    const float* __restrict__ be0, const float* __restrict__ m0,
    const float* __restrict__ v0, unsigned short* __restrict__ pbf)
{
  int b = blockIdx.x, l0 = blockIdx.y * 64;
  __shared__ float xs[71 * 4];
  __shared__ float sc[64], sb[64];
  int tid = threadIdx.x;
  for (int j = tid; j < 71; j += 256) {
    int l = l0 + j;
    float4 xv = (l < LL) ? *(const float4*)(x + ((size_t)b * LL + l) * EMB)
                         : make_float4(0.f, 0.f, 0.f, 0.f);
    *(float4*)(xs + j * 4) = xv;
  }
  if (tid < 64) {
    float s = g0[tid] * rsqrtf(v0[tid] + 1e-5f);
    sc[tid] = s;
    sb[tid] = (b0[tid] - m0[tid]) * s + be0[tid];
  }
  __syncthreads();
  int w = tid >> 6, lane = tid & 63, nl = lane & 15, quad = lane >> 4;
  const float* ap = xs + (w * 16 + nl) * 4 + quad;
  short8 af;
  #pragma unroll
  for (int j = 0; j < 8; ++j) af[j] = (short)bfr(ap[j * 4]);
  f32x4 acc[4];
  #pragma unroll
  for (int nt = 0; nt < 4; ++nt) {
    short8 bf = __builtin_bit_cast(short8,
        *(const uint4v*)(wbf0 + ((nt * 16 + nl) * 32 + quad * 8)));
    acc[nt] = (f32x4){0.f, 0.f, 0.f, 0.f};
    acc[nt] = __builtin_amdgcn_mfma_f32_16x16x32_bf16(af, bf, acc[nt], 0, 0, 0);
  }
  int t = (l0 >> 2) + w * 4 + quad;
  if (t < LP) {
    #pragma unroll
    for (int nt = 0; nt < 4; ++nt) {
      int c = nt * 16 + nl;
      float scc = sc[c], sbc = sb[c];
      float mx = -1e30f;
      #pragma unroll
      for (int r = 0; r < 4; ++r) mx = fmaxf(mx, acc[nt][r] * scc + sbc);
      pbf[((size_t)b * LP + t) * CC + c] = bfr(fmaxf(mx, 0.0f));
    }
  }
}

// ---------------- K2: conv1 as 8 shifted GEMMs (bf16 p, reordered weights) ----------------
__global__ __launch_bounds__(256) void k_conv1m(const unsigned short* __restrict__ pbf,
    const unsigned short* __restrict__ wbf1r,
    const float* __restrict__ b1, const float* __restrict__ g1,
    const float* __restrict__ be1, const float* __restrict__ m1,
    const float* __restrict__ v1, unsigned short* __restrict__ x2bf)
{
  int b = blockIdx.x, t0 = blockIdx.y * 64;
  __shared__ __align__(16) unsigned short ps[71 * 72];
  __shared__ float sc[64], sb[64];
  int tid = threadIdx.x;
  for (int j = tid; j < 71 * 32; j += 256) {
    int tl = j >> 5, cu = j & 31;
    int t = t0 + tl;
    unsigned v = (t < LP) ? *(const unsigned*)(pbf + ((size_t)b * LP + t) * CC + cu * 2) : 0u;
    *(unsigned*)(&ps[tl * 72 + cu * 2]) = v;
  }
  if (tid < 64) {
    float s = g1[tid] * rsqrtf(v1[tid] + 1e-5f);
    sc[tid] = s;
    sb[tid] = (b1[tid] - m1[tid]) * s + be1[tid];
  }
  __syncthreads();
  int w = tid >> 6, lane = tid & 63, nl = lane & 15, quad = lane >> 4;
  int tlb = w * 16 + nl;
  f32x4 acc[4];
  #pragma unroll
  for (int nt = 0; nt < 4; ++nt) acc[nt] = (f32x4){0.f, 0.f, 0.f, 0.f};
  #pragma unroll
  for (int k8 = 0; k8 < 8; ++k8) {
    short8 af0 = __builtin_bit_cast(short8,
        *(const uint4v*)(&ps[(tlb + k8) * 72 + 0 + quad * 8]));
    short8 af1 = __builtin_bit_cast(short8,
        *(const uint4v*)(&ps[(tlb + k8) * 72 + 32 + quad * 8]));
    #pragma unroll
    for (int nt = 0; nt < 4; ++nt) {
      int co = nt * 16 + nl;
      short8 bf0 = __builtin_bit_cast(short8,
          *(const uint4v*)(wbf1r + (size_t)co * 512 + k8 * 64 + 0 + quad * 8));
      short8 bf1 = __builtin_bit_cast(short8,
          *(const uint4v*)(wbf1r + (size_t)co * 512 + k8 * 64 + 32 + quad * 8));
      acc[nt] = __builtin_amdgcn_mfma_f32_16x16x32_bf16(af0, bf0, acc[nt], 0, 0, 0);
      acc[nt] = __builtin_amdgcn_mfma_f32_16x16x32_bf16(af1, bf1, acc[nt], 0, 0, 0);
    }
  }
  #pragma unroll
  for (int nt = 0; nt < 4; ++nt) {
    int c = nt * 16 + nl;
    float scc = sc[c], sbc = sb[c];
    #pragma unroll
    for (int r = 0; r < 4; ++r) {
      int t = t0 + w * 16 + quad * 4 + r;
      if (t < TT)
        x2bf[((size_t)b * TT + t) * CC + c] = bfr(fmaxf(acc[nt][r] * scc + sbc, 0.0f));
    }
  }
}

// ---------------- K3: bi-LSTM via MFMA, 1 chain/block, X-GEMM software-pipelined ----------
// 64 blocks (32 batch-tiles x 2 dir), 4 waves. Per step the post-barrier critical path is
// only 2 H-MFMAs + gate VALU; the X-projection for step s+1 is computed during step s
// (x loaded 2 steps ahead) on the otherwise-idle matrix pipe. Gate math uses exp2-prescaled
// weights and a fused single-rcp form for i*tanh(g).
__global__ __launch_bounds__(256) void k_lstm_m(const unsigned short* __restrict__ x2bf,
    const unsigned short* __restrict__ wihbf, const unsigned short* __restrict__ whhbf,
    const float* __restrict__ lbias,
    unsigned short* __restrict__ values, float* __restrict__ hT)
{
  int dir = blockIdx.y;
  int b0 = blockIdx.x * 16;
  int tid = threadIdx.x;
  int w = tid >> 6, lane = tid & 63, l15 = lane & 15, quad = lane >> 4;
  int h0 = w * 16;
  const unsigned short* wih = wihbf + dir * 16384;
  const unsigned short* whh = whhbf + dir * 16384;

  short8 bx[4][2], bh[4][2];
  float bias_v[4];
  #pragma unroll
  for (int g = 0; g < 4; ++g) {
    int row = g * 64 + h0 + l15;
    #pragma unroll
    for (int k = 0; k < 2; ++k) {
      bx[g][k] = __builtin_bit_cast(short8, *(const uint4v*)(wih + row * 64 + k * 32 + quad * 8));
      bh[g][k] = __builtin_bit_cast(short8, *(const uint4v*)(whh + row * 64 + k * 32 + quad * 8));
    }
    bias_v[g] = lbias[dir * 256 + g * 64 + h0 + l15];
  }

  __shared__ __align__(16) unsigned short hist[8][16 * 72];
  for (int j = tid; j < 16 * 72; j += 256) hist[7][j] = 0;   // h_{-1} = 0
  __syncthreads();

  // per-lane x base: A-frag row = batch l15, k = quad*8 (+32 for upper half)
  const unsigned short* xp = x2bf + ((size_t)(b0 + l15) * TT) * 64 + quad * 8;

  uint4v xr[2][2];   // [parity][half]; x(s) lives in slot s&1
  f32x4 aX[2][4];    // X-projection (+bias) for step s in slot s&1
  {
    size_t o0 = (size_t)(dir ? (TT - 1) : 0) * 64;
    xr[0][0] = *(const uint4v*)(xp + o0);
    xr[0][1] = *(const uint4v*)(xp + o0 + 32);
    short8 a0 = __builtin_bit_cast(short8, xr[0][0]);
    short8 a1 = __builtin_bit_cast(short8, xr[0][1]);
    #pragma unroll
    for (int g = 0; g < 4; ++g) {
      aX[0][g] = (f32x4){bias_v[g], bias_v[g], bias_v[g], bias_v[g]};
      aX[0][g] = __builtin_amdgcn_mfma_f32_16x16x32_bf16(a0, bx[g][0], aX[0][g], 0, 0, 0);
      aX[0][g] = __builtin_amdgcn_mfma_f32_16x16x32_bf16(a1, bx[g][1], aX[0][g], 0, 0, 0);
    }
    size_t o1 = (size_t)(dir ? (TT - 2) : 1) * 64;
    xr[1][0] = *(const uint4v*)(xp + o1);
    xr[1][1] = *(const uint4v*)(xp + o1 + 32);
  }

  float cst[4] = {0.f, 0.f, 0.f, 0.f};

  for (int c = 0; c < 31; ++c) {
    #pragma unroll
    for (int sl = 0; sl < 8; ++sl) {
      int s = c * 8 + sl;
      const int par = sl & 1;
      if (s < TT) {
        int hp = (sl + 7) & 7;
        // post-barrier critical path: 2 dependent H-MFMAs per gate
        short8 ah0 = __builtin_bit_cast(short8, *(const uint4v*)(&hist[hp][l15 * 72 + quad * 8]));
        short8 ah1 = __builtin_bit_cast(short8, *(const uint4v*)(&hist[hp][l15 * 72 + 32 + quad * 8]));
        f32x4 aH[4];
        #pragma unroll
        for (int g = 0; g < 4; ++g) {
          aH[g] = (f32x4){0.f, 0.f, 0.f, 0.f};
          aH[g] = __builtin_amdgcn_mfma_f32_16x16x32_bf16(ah0, bh[g][0], aH[g], 0, 0, 0);
          aH[g] = __builtin_amdgcn_mfma_f32_16x16x32_bf16(ah1, bh[g][1], aH[g], 0, 0, 0);
        }
        // off-critical-path: X projection for step s+1 (x was loaded at step s-1)
        {
          short8 a0 = __builtin_bit_cast(short8, xr[par ^ 1][0]);
          short8 a1 = __builtin_bit_cast(short8, xr[par ^ 1][1]);
          #pragma unroll
          for (int g = 0; g < 4; ++g) {
            aX[par ^ 1][g] = (f32x4){bias_v[g], bias_v[g], bias_v[g], bias_v[g]};
            aX[par ^ 1][g] = __builtin_amdgcn_mfma_f32_16x16x32_bf16(a0, bx[g][0], aX[par ^ 1][g], 0, 0, 0);
            aX[par ^ 1][g] = __builtin_amdgcn_mfma_f32_16x16x32_bf16(a1, bx[g][1], aX[par ^ 1][g], 0, 0, 0);
          }
        }
        // issue load of x(s+2) into the slot x(s) just vacated
        {
          int sn = s + 2; if (sn > TT - 1) sn = TT - 1;
          size_t on = (size_t)(dir ? (TT - 1 - sn) : sn) * 64;
          xr[par][0] = *(const uint4v*)(xp + on);
          xr[par][1] = *(const uint4v*)(xp + on + 32);
        }
        #pragma unroll
        for (int r = 0; r < 4; ++r) {
          float yi = aX[par][0][r] + aH[0][r];
          float yf = aX[par][1][r] + aH[1][r];
          float yg = aX[par][2][r] + aH[2][r];
          float yo = aX[par][3][r] + aH[3][r];
          float Fi = ex2(-yi);                 // e^-i (prescaled)
          float Ff = ex2(-yf);
          float Eg = ex2(yg);                  // e^{2g} (prescaled by 2log2e)
          float fg = __builtin_amdgcn_rcpf(1.0f + Ff);
          float igg = (Eg - 1.0f) * __builtin_amdgcn_rcpf((1.0f + Fi) * (Eg + 1.0f));
          cst[r] = fg * cst[r] + igg;
          float og = __builtin_amdgcn_rcpf(1.0f + ex2(-yo));
          float hh = og * tanh2(cst[r] * TL2E);
          hist[sl][(quad * 4 + r) * 72 + h0 + l15] = bfr(hh);
          if (s == TT - 1) {
            int bglob = b0 + quad * 4 + r;
            hT[((size_t)dir * BB + bglob) * 64 + h0 + l15] = hh;
          }
        }
      }
      lds_barrier();
    }
    // store values for this chunk; vmcnt not waited at lds_barrier
    #pragma unroll
    for (int i = 0; i < 4; ++i) {
      int flat = i * 256 + tid;
      int sl2 = flat >> 7, wb = (flat >> 3) & 15, c8 = flat & 7;
      int s = c * 8 + sl2;
      if (s < TT) {
        uint4v dv = *(const uint4v*)(&hist[sl2][wb * 72 + c8 * 8]);
        int t = dir ? (TT - 1 - s) : s;
        *(uint4v*)(values + ((size_t)(b0 + wb) * TT + t) * D2 + dir * 64 + c8 * 8) = dv;
      }
    }
    lds_barrier();   // protect hist[0] overwrite in next chunk
  }
}

// ---------------- K3b: q2 = h_n @ W2^T + W2_b ----------------
__global__ __launch_bounds__(128) void k_q2(const float* __restrict__ hT,
    const float* __restrict__ W2, const float* __restrict__ W2b,
    float* __restrict__ q2)
{
  int b = blockIdx.x;
  int tid = threadIdx.x;
  __shared__ float4 hn4[32];
  ((float*)hn4)[tid] = hT[(size_t)b * 128 + tid];
  __syncthreads();
  const float4* w4 = (const float4*)(W2 + (size_t)tid * 128);
  float a = W2b[tid];
  #pragma unroll
  for (int j = 0; j < 32; ++j) {
    float4 w = w4[j]; float4 h = hn4[j];
    a += w.x * h.x + w.y * h.y + w.z * h.z + w.w * h.w;
  }
  q2[(size_t)b * 128 + tid] = a;
}

// ---------------- K4: score via MFMA -> scoreT[b][n][t] bf16 ----------------
__global__ __launch_bounds__(256) void k_score_m(const unsigned short* __restrict__ vbf,
    const unsigned short* __restrict__ W1bf, const float* __restrict__ W1b,
    const float* __restrict__ q2, const unsigned short* __restrict__ Vbf,
    const float* __restrict__ Vb, unsigned short* __restrict__ scoreT)
{
  int b = blockIdx.x, t0 = blockIdx.y * 64;
  int tid = threadIdx.x, w = tid >> 6, lane = tid & 63, l15 = lane & 15, quad = lane >> 4;
  __shared__ unsigned short us[64 * 136];
  __shared__ unsigned short sc2[64 * 213];
  const unsigned short* arow = vbf + ((size_t)b * TT + t0 + w * 16 + l15) * 128;
  short8 ax[4];
  #pragma unroll
  for (int ks = 0; ks < 4; ++ks)
    ax[ks] = __builtin_bit_cast(short8, *(const uint4v*)(arow + ks * 32 + quad * 8));
  #pragma unroll
  for (int nt = 0; nt < 8; ++nt) {
    int n = nt * 16 + l15;
    float base = W1b[n] + q2[(size_t)b * 128 + n];
    f32x4 acc = (f32x4){base, base, base, base};
    #pragma unroll
    for (int ks = 0; ks < 4; ++ks) {
      short8 bf = __builtin_bit_cast(short8,
          *(const uint4v*)(W1bf + (size_t)n * 128 + ks * 32 + quad * 8));
      acc = __builtin_amdgcn_mfma_f32_16x16x32_bf16(ax[ks], bf, acc, 0, 0, 0);
    }
    #pragma unroll
    for (int r = 0; r < 4; ++r)
      us[(w * 16 + quad * 4 + r) * 136 + nt * 16 + l15] = bfr(tanhff(acc[r]));
  }
  __syncthreads();
  short8 au[4];
  #pragma unroll
  for (int ks = 0; ks < 4; ++ks)
    au[ks] = __builtin_bit_cast(short8, *(const uint4v*)(&us[(w * 16 + l15) * 136 + ks * 32 + quad * 8]));
  for (int nt2 = 0; nt2 < 13; ++nt2) {
    int n = nt2 * 16 + l15;
    float b2 = (n < NTF) ? Vb[n] : 0.0f;
    f32x4 a2 = (f32x4){b2, b2, b2, b2};
    #pragma unroll
    for (int ks = 0; ks < 4; ++ks) {
      short8 bf = __builtin_bit_cast(short8,
          *(const uint4v*)(Vbf + (size_t)n * 128 + ks * 32 + quad * 8));
      a2 = __builtin_amdgcn_mfma_f32_16x16x32_bf16(au[ks], bf, a2, 0, 0, 0);
    }
    #pragma unroll
    for (int r = 0; r < 4; ++r) {
      int tl = w * 16 + quad * 4 + r;
      sc2[tl * 213 + n] = bfr(a2[r]);
    }
  }
  __syncthreads();
  int tg = tid & 3;
  #pragma unroll
  for (int pp = 0; pp < 4; ++pp) {
    int nrow = pp * 64 + (tid >> 2);
    if (nrow < NTF) {
      unsigned uu[8];
      #pragma unroll
      for (int k2 = 0; k2 < 8; ++k2) {
        unsigned lo = sc2[(tg * 16 + k2 * 2) * 213 + nrow];
        unsigned hi = sc2[(tg * 16 + k2 * 2 + 1) * 213 + nrow];
        uu[k2] = lo | (hi << 16);
      }
      size_t dst = ((size_t)b * 208 + nrow) * 256 + t0 + tg * 16;
      *(uint4v*)(scoreT + dst) = (uint4v){uu[0], uu[1], uu[2], uu[3]};
      *(uint4v*)(scoreT + dst + 8) = (uint4v){uu[4], uu[5], uu[6], uu[7]};
    }
  }
}

// ---------------- K5: softmax over t, row-wise on scoreT ----------------
__global__ __launch_bounds__(256) void k_softmax(unsigned short* __restrict__ scoreT,
    float* __restrict__ sinv)
{
  int b = blockIdx.x, nc = blockIdx.y;
  int tid = threadIdx.x;
  int n = nc * 64 + (tid >> 2), tg = tid & 3;
  if (n >= NTF) return;
  unsigned short* row = scoreT + ((size_t)b * 208 + n) * 256 + tg * 64;
  uint4v ld[8];
  #pragma unroll
  for (int i = 0; i < 8; ++i) ld[i] = *(const uint4v*)(row + i * 8);
  float m = -1e30f;
  #pragma unroll
  for (int i = 0; i < 8; ++i) {
    #pragma unroll
    for (int u = 0; u < 4; ++u) {
      unsigned xv = ld[i][u];
      int t0 = tg * 64 + i * 8 + u * 2;
      float a = __builtin_bit_cast(float, xv << 16);
      float c = __builtin_bit_cast(float, xv & 0xffff0000u);
      if (t0 < TT) m = fmaxf(m, a);
      if (t0 + 1 < TT) m = fmaxf(m, c);
    }
  }
  m = fmaxf(m, __shfl_xor(m, 1, 64));
  m = fmaxf(m, __shfl_xor(m, 2, 64));
  float s = 0.0f;
  #pragma unroll
  for (int i = 0; i < 8; ++i) {
    uint4v ov;
    #pragma unroll
    for (int u = 0; u < 4; ++u) {
      unsigned xv = ld[i][u];
      int t0 = tg * 64 + i * 8 + u * 2;
      float a = __builtin_bit_cast(float, xv << 16);
      float c = __builtin_bit_cast(float, xv & 0xffff0000u);
      float ea = (t0 < TT) ? __expf(a - m) : 0.0f;
      float ec = (t0 + 1 < TT) ? __expf(c - m) : 0.0f;
      s += ea + ec;
      ov[u] = (unsigned)bfr(ea) | ((unsigned)bfr(ec) << 16);
    }
    *(uint4v*)(row + i * 8) = ov;
  }
  s += __shfl_xor(s, 1, 64);
  s += __shfl_xor(s, 2, 64);
  if (tg == 0) sinv[(size_t)b * NTF + n] = __builtin_amdgcn_rcpf(s);
}

// ---------------- K6: context via MFMA -> ctxbf (bf16, [n][b][d] layout) ----------------
__global__ __launch_bounds__(256) void k_ctx_m(const unsigned short* __restrict__ vbf,
    const unsigned short* __restrict__ scoreT, const float* __restrict__ sinv,
    unsigned short* __restrict__ ctxbf)
{
  int b = blockIdx.x;
  int tid = threadIdx.x, w = tid >> 6, lane = tid & 63, l15 = lane & 15, quad = lane >> 4;
  __shared__ __align__(16) unsigned short vt[128 * 264];  // [d][t]
  __shared__ float sls[208];
  for (int flat = tid; flat < 247 * 64; flat += 256) {
    int t = flat >> 6, dp = flat & 63;
    unsigned v = *(const unsigned*)(vbf + ((size_t)b * TT + t) * D2 + dp * 2);
    vt[(dp * 2) * 264 + t] = (unsigned short)(v & 0xffffu);
    vt[(dp * 2 + 1) * 264 + t] = (unsigned short)(v >> 16);
  }
  for (int j = tid; j < 128 * 9; j += 256) {
    int d = j / 9, t = 247 + (j % 9);
    vt[d * 264 + t] = 0;
  }
  for (int j = tid; j < 208; j += 256) sls[j] = (j < NTF) ? sinv[(size_t)b * NTF + j] : 0.0f;
  __syncthreads();

  const unsigned short* abase = scoreT + (size_t)b * 208 * 256;
  for (int mi = 0; mi < 4; ++mi) {
    int mt = w + 4 * mi;
    if (mt >= 13) continue;
    const unsigned short* arow = abase + (size_t)(mt * 16 + l15) * 256;
    short8 af[8];
    #pragma unroll
    for (int ks = 0; ks < 8; ++ks)
      af[ks] = __builtin_bit_cast(short8, *(const uint4v*)(arow + ks * 32 + quad * 8));
    f32x4 acc[8];
    #pragma unroll
    for (int dt = 0; dt < 8; ++dt) {
      acc[dt] = (f32x4){0.f, 0.f, 0.f, 0.f};
      #pragma unroll
      for (int ks = 0; ks < 8; ++ks) {
        short8 bf = __builtin_bit_cast(short8,
            *(const uint4v*)(&vt[(dt * 16 + l15) * 264 + ks * 32 + quad * 8]));
        acc[dt] = __builtin_amdgcn_mfma_f32_16x16x32_bf16(af[ks], bf, acc[dt], 0, 0, 0);
      }
    }
    #pragma unroll
    for (int r = 0; r < 4; ++r) {
      int n = mt * 16 + quad * 4 + r;
      if (n < NTF) {
        float rs = sls[n];
        #pragma unroll
        for (int dt = 0; dt < 8; ++dt)
          ctxbf[((size_t)n * BB + b) * D2 + dt * 16 + l15] = bfr(acc[dt][r] * rs);
      }
    }
  }
}

// ---------------- K7: per-TF heads via MFMA (coalesced [n][b][d] ctx reads) ----------------
__global__ __launch_bounds__(256) void k_heads_m(const unsigned short* __restrict__ ctxbf,
    const unsigned short* __restrict__ f1bf, const float* __restrict__ fc1b,
    const float* __restrict__ fc2w, const float* __restrict__ fc2b,
    float* __restrict__ out)
{
  int n = blockIdx.x;
  int b0 = blockIdx.y * 128;
  int tid = threadIdx.x, w = tid >> 6, lane = tid & 63, l15 = lane & 15, quad = lane >> 4;
  // B-frags: fc1 rows for o = nt*16+l15 (resident)
  short8 bfr_[4][4];
  float f1bv[4], f2v[4];
  #pragma unroll
  for (int nt = 0; nt < 4; ++nt) {
    int o = nt * 16 + l15;
    #pragma unroll
    for (int ks = 0; ks < 4; ++ks)
      bfr_[nt][ks] = __builtin_bit_cast(short8,
          *(const uint4v*)(f1bf + ((size_t)n * 64 + o) * 128 + ks * 32 + quad * 8));
    f1bv[nt] = fc1b[n * 64 + o];
    f2v[nt] = fc2w[n * 64 + o];
  }
  float f2b = fc2b[n];
  #pragma unroll
  for (int mi = 0; mi < 2; ++mi) {
    int m16 = (w * 2 + mi) * 16;
    const unsigned short* arow = ctxbf + ((size_t)n * BB + (b0 + m16 + l15)) * 128;
    short8 af[4];
    #pragma unroll
    for (int ks = 0; ks < 4; ++ks)
      af[ks] = __builtin_bit_cast(short8, *(const uint4v*)(arow + ks * 32 + quad * 8));
    f32x4 acc[4];
    #pragma unroll
    for (int nt = 0; nt < 4; ++nt) {
      acc[nt] = (f32x4){0.f, 0.f, 0.f, 0.f};
      #pragma unroll
      for (int ks = 0; ks < 4; ++ks)
        acc[nt] = __builtin_amdgcn_mfma_f32_16x16x32_bf16(af[ks], bfr_[nt][ks], acc[nt], 0, 0, 0);
    }
    #pragma unroll
    for (int r = 0; r < 4; ++r) {
      float part = 0.0f;
      #pragma unroll
      for (int nt = 0; nt < 4; ++nt)
        part += fmaxf(acc[nt][r] + f1bv[nt], 0.0f) * f2v[nt];
      part += __shfl_xor(part, 1, 64);
      part += __shfl_xor(part, 2, 64);
      part += __shfl_xor(part, 4, 64);
      part += __shfl_xor(part, 8, 64);
      if (l15 == 0) {
        int bb = b0 + m16 + quad * 4 + r;
        out[(size_t)bb * NTF + n] = part + f2b;
      }
    }
  }
}

extern "C" void kernel_launch(void* const* d_in, const int* in_sizes, int n_in,
                              void* d_out, int out_size, void* d_ws, size_t ws_size,
                              hipStream_t stream)
{
  const float* x    = (const float*)d_in[0];
  const float* c0w  = (const float*)d_in[1];
  const float* c0b  = (const float*)d_in[2];
  const float* g0   = (const float*)d_in[3];
  const float* be0  = (const float*)d_in[4];
  const float* m0   = (const float*)d_in[5];
  const float* v0   = (const float*)d_in[6];
  const float* c1w  = (const float*)d_in[7];
  const float* c1b  = (const float*)d_in[8];
  const float* g1   = (const float*)d_in[9];
  const float* be1  = (const float*)d_in[10];
  const float* m1   = (const float*)d_in[11];
  const float* v1   = (const float*)d_in[12];
  const float* wihf = (const float*)d_in[13];
  const float* whhf = (const float*)d_in[14];
  const float* bihf = (const float*)d_in[15];
  const float* bhhf = (const float*)d_in[16];
  const float* wihb = (const float*)d_in[17];
  const float* whhb = (const float*)d_in[18];
  const float* bihb = (const float*)d_in[19];
  const float* bhhb = (const float*)d_in[20];
  const float* W1w  = (const float*)d_in[21];
  const float* W1b  = (const float*)d_in[22];
  const float* W2w  = (const float*)d_in[23];
  const float* W2b  = (const float*)d_in[24];
  const float* Vw   = (const float*)d_in[25];
  const float* Vb   = (const float*)d_in[26];
  const float* f1w  = (const float*)d_in[27];
  const float* f1b  = (const float*)d_in[28];
  const float* f2w  = (const float*)d_in[29];
  const float* f2b  = (const float*)d_in[30];

  float* ws = (float*)d_ws;
  unsigned short* scoreT = (unsigned short*)ws;            // [b][208][256] bf16
  unsigned short* pbf  = (unsigned short*)ws;              // overlaps scoreT region (dead first)
  unsigned short* x2bf = (unsigned short*)(ws + 8323072);
  unsigned short* vbf  = (unsigned short*)(ws + 25292800);
  float* hT     = ws + 33387520;
  float* q2     = ws + 33453056;
  float* sinv   = ws + 33518592;
  unsigned short* ctxbf = (unsigned short*)(ws + 33620992); // [n][b][d] bf16
  unsigned short* wbf0  = (unsigned short*)(ws + 46728192);
  unsigned short* wbf1r = (unsigned short*)(ws + 46729216);
  unsigned short* wihbf = (unsigned short*)(ws + 46745600);
  unsigned short* whhbf = (unsigned short*)(ws + 46761984);
  float* lbias          = ws + 46778368;
  unsigned short* W1bf  = (unsigned short*)(ws + 46778880);
  unsigned short* Vbf   = (unsigned short*)(ws + 46787072);
  unsigned short* f1bf  = (unsigned short*)(ws + 46800384); // 1,638,400 shorts
  float* out    = (float*)d_out;

  k_cvt<<<dim3(6400), 256, 0, stream>>>(c0w, c1w, wihf, whhf, wihb, whhb,
                                        bihf, bhhf, bihb, bhhb, W1w, Vw, f1w,
                                        wbf0, wbf1r, wihbf, whhbf, lbias, W1bf, Vbf, f1bf);
  k_conv0m<<<dim3(BB, 16), 256, 0, stream>>>(x, wbf0, c0b, g0, be0, m0, v0, pbf);
  k_conv1m<<<dim3(BB, 4), 256, 0, stream>>>(pbf, wbf1r, c1b, g1, be1, m1, v1, x2bf);
  k_lstm_m<<<dim3(BB / 16, 2), 256, 0, stream>>>(x2bf, wihbf, whhbf, lbias, vbf, hT);
  k_q2<<<dim3(BB), 128, 0, stream>>>(hT, W2w, W2b, q2);
  k_score_m<<<dim3(BB, 4), 256, 0, stream>>>(vbf, W1bf, W1b, q2, Vbf, Vb, scoreT);
  k_softmax<<<dim3(BB, 4), 256, 0, stream>>>(scoreT, sinv);
  k_ctx_m<<<dim3(BB), 256, 0, stream>>>(vbf, scoreT, sinv, ctxbf);
  k_heads_m<<<dim3(NTF, 4), 256, 0, stream>>>(ctxbf, f1bf, f1b, f2w, f2b, out);
}

// Round 3
// 481.365 us; speedup vs baseline: 1.2431x; 1.0879x over previous
//
#include <hip/hip_runtime.h>
#include <math.h>

#define BB 512
#define LL 1024
#define EMB 4
#define CC 64
#define NTF 200
#define TT 247      // seq len after conv1
#define LP 254      // after pool
#define D2 128

typedef __attribute__((ext_vector_type(8))) short short8;
typedef __attribute__((ext_vector_type(4))) float f32x4;
typedef __attribute__((ext_vector_type(4))) unsigned int uint4v;

#define L2E  1.4426950408889634f   // log2(e)
#define TL2E 2.8853900817779268f   // 2*log2(e)

__device__ __forceinline__ float tanhff(float x) {
  return 1.0f - 2.0f * __builtin_amdgcn_rcpf(__expf(2.0f * x) + 1.0f);
}

// exp2 native (v_exp_f32 computes 2^x)
__device__ __forceinline__ float ex2(float x) {
  return __builtin_amdgcn_exp2f(x);
}
// y is the preactivation already scaled by 2*log2(e)
__device__ __forceinline__ float tanh2(float y) {
  return 1.0f - 2.0f * __builtin_amdgcn_rcpf(ex2(y) + 1.0f);
}

// LDS-only barrier: 0xC07F = vmcnt(63)|expcnt(7)|lgkmcnt(0).
__device__ __forceinline__ void lds_barrier() {
  __builtin_amdgcn_s_waitcnt(0xC07F);
  __builtin_amdgcn_s_barrier();
}

// f32 -> bf16 round-to-nearest-even (finite inputs)
__device__ __forceinline__ unsigned short bfr(float f) {
  unsigned u = __builtin_bit_cast(unsigned, f);
  u += 0x7fffu + ((u >> 16) & 1u);
  return (unsigned short)(u >> 16);
}

// ---------------- K0: weight conversions ----------------
// grid 1600*256; f1bf converted 4/thread (vectorized). wbf1r is w1 REORDERED to [co][k][ci].
// LSTM gate weights/biases PRE-SCALED by log2(e) (2*log2e for g gate) -> native exp2 gates.
__global__ __launch_bounds__(256) void k_cvt(const float* __restrict__ w0,
    const float* __restrict__ w1,
    const float* __restrict__ wihf, const float* __restrict__ whhf,
    const float* __restrict__ wihb, const float* __restrict__ whhb,
    const float* __restrict__ bihf, const float* __restrict__ bhhf,
    const float* __restrict__ bihb, const float* __restrict__ bhhb,
    const float* __restrict__ W1w, const float* __restrict__ Vw,
    const float* __restrict__ f1w,
    unsigned short* __restrict__ wbf0, unsigned short* __restrict__ wbf1r,
    unsigned short* __restrict__ wihbf, unsigned short* __restrict__ whhbf,
    float* __restrict__ lbias,
    unsigned short* __restrict__ W1bf, unsigned short* __restrict__ Vbf,
    unsigned short* __restrict__ f1bf)
{
  int i = blockIdx.x * 256 + threadIdx.x;
  if (i < 2048) wbf0[i] = bfr(w0[i]);
  if (i < 32768) {                           // dst [co][k][ci] <- src [co][ci][k]
    int co = i >> 9, k = (i >> 6) & 7, ci = i & 63;
    wbf1r[i] = bfr(w1[co * 512 + ci * 8 + k]);
  }
  if (i < 16384) {
    float s = ((i >> 12) == 2) ? TL2E : L2E;  // gate = row>>6 = i>>12
    wihbf[i] = bfr(wihf[i] * s);
    wihbf[16384 + i] = bfr(wihb[i] * s);
    whhbf[i] = bfr(whhf[i] * s);
    whhbf[16384 + i] = bfr(whhb[i] * s);
    W1bf[i] = bfr(W1w[i]);                    // attention W1: unscaled
  }
  if (i < 26624) {                           // Vbf padded to 208 rows
    int row = i >> 7;
    Vbf[i] = (row < NTF) ? bfr(Vw[i]) : (unsigned short)0;
  }
  if (i < 256) {
    float s = ((i >> 6) == 2) ? TL2E : L2E;
    lbias[i] = (bihf[i] + bhhf[i]) * s;
    lbias[256 + i] = (bihb[i] + bhhb[i]) * s;
  }
  {
    int i4 = i * 4;
    if (i4 < 1638400) {                      // [n][o][k] flat, 4 elems/thread
      float4 v = *(const float4*)(f1w + i4);
      f1bf[i4 + 0] = bfr(v.x);
      f1bf[i4 + 1] = bfr(v.y);
      f1bf[i4 + 2] = bfr(v.z);
      f1bf[i4 + 3] = bfr(v.w);
    }
  }
}

// ---------------- K1: conv0 + BN + ReLU + maxpool(4), MFMA -> pbf (bf16) ----------------
__global__ __launch_bounds__(256) void k_conv0m(const float* __restrict__ x,
    const unsigned short* __restrict__ wbf0,
    const float* __restrict__ b0, const float* __restrict__ g0,
    const float* __restrict__ be0, const float* __restrict__ m0,
    const float* __restrict__ v0, unsigned short* __restrict__ pbf)
{
  int b = blockIdx.x, l0 = blockIdx.y * 64;
  __shared__ float xs[71 * 4];
  __shared__ float sc[64], sb[64];
  int tid = threadIdx.x;
  for (int j = tid; j < 71; j += 256) {
    int l = l0 + j;
    float4 xv = (l < LL) ? *(const float4*)(x + ((size_t)b * LL + l) * EMB)
                         : make_float4(0.f, 0.f, 0.f, 0.f);
    *(float4*)(xs + j * 4) = xv;
  }
  if (tid < 64) {
    float s = g0[tid] * rsqrtf(v0[tid] + 1e-5f);
    sc[tid] = s;
    sb[tid] = (b0[tid] - m0[tid]) * s + be0[tid];
  }
  __syncthreads();
  int w = tid >> 6, lane = tid & 63, nl = lane & 15, quad = lane >> 4;
  const float* ap = xs + (w * 16 + nl) * 4 + quad;
  short8 af;
  #pragma unroll
  for (int j = 0; j < 8; ++j) af[j] = (short)bfr(ap[j * 4]);
  f32x4 acc[4];
  #pragma unroll
  for (int nt = 0; nt < 4; ++nt) {
    short8 bf = __builtin_bit_cast(short8,
        *(const uint4v*)(wbf0 + ((nt * 16 + nl) * 32 + quad * 8)));
    acc[nt] = (f32x4){0.f, 0.f, 0.f, 0.f};
    acc[nt] = __builtin_amdgcn_mfma_f32_16x16x32_bf16(af, bf, acc[nt], 0, 0, 0);
  }
  int t = (l0 >> 2) + w * 4 + quad;
  if (t < LP) {
    #pragma unroll
    for (int nt = 0; nt < 4; ++nt) {
      int c = nt * 16 + nl;
      float scc = sc[c], sbc = sb[c];
      float mx = -1e30f;
      #pragma unroll
      for (int r = 0; r < 4; ++r) mx = fmaxf(mx, acc[nt][r] * scc + sbc);
      pbf[((size_t)b * LP + t) * CC + c] = bfr(fmaxf(mx, 0.0f));
    }
  }
}

// ---------------- K2: conv1 as 8 shifted GEMMs (bf16 p, reordered weights) ----------------
__global__ __launch_bounds__(256) void k_conv1m(const unsigned short* __restrict__ pbf,
    const unsigned short* __restrict__ wbf1r,
    const float* __restrict__ b1, const float* __restrict__ g1,
    const float* __restrict__ be1, const float* __restrict__ m1,
    const float* __restrict__ v1, unsigned short* __restrict__ x2bf)
{
  int b = blockIdx.x, t0 = blockIdx.y * 64;
  __shared__ __align__(16) unsigned short ps[71 * 72];
  __shared__ float sc[64], sb[64];
  int tid = threadIdx.x;
  for (int j = tid; j < 71 * 32; j += 256) {
    int tl = j >> 5, cu = j & 31;
    int t = t0 + tl;
    unsigned v = (t < LP) ? *(const unsigned*)(pbf + ((size_t)b * LP + t) * CC + cu * 2) : 0u;
    *(unsigned*)(&ps[tl * 72 + cu * 2]) = v;
  }
  if (tid < 64) {
    float s = g1[tid] * rsqrtf(v1[tid] + 1e-5f);
    sc[tid] = s;
    sb[tid] = (b1[tid] - m1[tid]) * s + be1[tid];
  }
  __syncthreads();
  int w = tid >> 6, lane = tid & 63, nl = lane & 15, quad = lane >> 4;
  int tlb = w * 16 + nl;
  f32x4 acc[4];
  #pragma unroll
  for (int nt = 0; nt < 4; ++nt) acc[nt] = (f32x4){0.f, 0.f, 0.f, 0.f};
  #pragma unroll
  for (int k8 = 0; k8 < 8; ++k8) {
    short8 af0 = __builtin_bit_cast(short8,
        *(const uint4v*)(&ps[(tlb + k8) * 72 + 0 + quad * 8]));
    short8 af1 = __builtin_bit_cast(short8,
        *(const uint4v*)(&ps[(tlb + k8) * 72 + 32 + quad * 8]));
    #pragma unroll
    for (int nt = 0; nt < 4; ++nt) {
      int co = nt * 16 + nl;
      short8 bf0 = __builtin_bit_cast(short8,
          *(const uint4v*)(wbf1r + (size_t)co * 512 + k8 * 64 + 0 + quad * 8));
      short8 bf1 = __builtin_bit_cast(short8,
          *(const uint4v*)(wbf1r + (size_t)co * 512 + k8 * 64 + 32 + quad * 8));
      acc[nt] = __builtin_amdgcn_mfma_f32_16x16x32_bf16(af0, bf0, acc[nt], 0, 0, 0);
      acc[nt] = __builtin_amdgcn_mfma_f32_16x16x32_bf16(af1, bf1, acc[nt], 0, 0, 0);
    }
  }
  #pragma unroll
  for (int nt = 0; nt < 4; ++nt) {
    int c = nt * 16 + nl;
    float scc = sc[c], sbc = sb[c];
    #pragma unroll
    for (int r = 0; r < 4; ++r) {
      int t = t0 + w * 16 + quad * 4 + r;
      if (t < TT)
        x2bf[((size_t)b * TT + t) * CC + c] = bfr(fmaxf(acc[nt][r] * scc + sbc, 0.0f));
    }
  }
}

// ---------------- K3: bi-LSTM via MFMA (R0 structure: xls LDS staging, chunked I/O) ------
// Gate math: exp2-prescaled weights, fused single-rcp form for sigmoid(i)*tanh(g).
__global__ __launch_bounds__(256) void k_lstm_m(const unsigned short* __restrict__ x2bf,
    const unsigned short* __restrict__ wihbf, const unsigned short* __restrict__ whhbf,
    const float* __restrict__ lbias,
    unsigned short* __restrict__ values, float* __restrict__ hT)
{
  int b0 = blockIdx.x * 16;
  int dir = blockIdx.y;
  int tid = threadIdx.x;
  int w = tid >> 6, lane = tid & 63, l15 = lane & 15, quad = lane >> 4;
  int h0 = w * 16;
  const unsigned short* wih = wihbf + dir * 16384;
  const unsigned short* whh = whhbf + dir * 16384;

  short8 bx[4][2], bh[4][2];
  float bias_v[4];
  #pragma unroll
  for (int g = 0; g < 4; ++g) {
    int row = g * 64 + h0 + l15;
    #pragma unroll
    for (int k = 0; k < 2; ++k) {
      bx[g][k] = __builtin_bit_cast(short8, *(const uint4v*)(wih + row * 64 + k * 32 + quad * 8));
      bh[g][k] = __builtin_bit_cast(short8, *(const uint4v*)(whh + row * 64 + k * 32 + quad * 8));
    }
    bias_v[g] = lbias[dir * 256 + g * 64 + h0 + l15];
  }

  __shared__ __align__(16) unsigned short xls[2][8][16 * 72];
  __shared__ __align__(16) unsigned short hist[8][16 * 72];
  for (int j = tid; j < 16 * 72; j += 256) hist[7][j] = 0;  // h_{-1} = 0

  int bl = tid >> 4, d4 = tid & 15;
  const unsigned short* xrow = x2bf + ((size_t)(b0 + bl) * TT) * 64 + d4 * 4;

  uint2 xr[8];
  #pragma unroll
  for (int k = 0; k < 8; ++k) {               // chunk 0
    int t = dir ? (TT - 1 - k) : k;
    xr[k] = *(const uint2*)(xrow + (size_t)t * 64);
  }
  #pragma unroll
  for (int k = 0; k < 8; ++k)
    *(uint2*)(&xls[0][k][bl * 72 + d4 * 4]) = xr[k];
  #pragma unroll
  for (int k = 0; k < 8; ++k) {               // chunk 1
    int s = 8 + k;
    int t = dir ? (TT - 1 - s) : s;
    xr[k] = *(const uint2*)(xrow + (size_t)t * 64);
  }
  __syncthreads();

  float cst[4] = {0.f, 0.f, 0.f, 0.f};
  for (int c = 0; c < 31; ++c) {
    int buf = c & 1;
    #pragma unroll
    for (int sl = 0; sl < 8; ++sl) {
      int hp = (sl + 7) & 7;
      short8 ax0 = __builtin_bit_cast(short8, *(const uint4v*)(&xls[buf][sl][l15 * 72 + quad * 8]));
      short8 ax1 = __builtin_bit_cast(short8, *(const uint4v*)(&xls[buf][sl][l15 * 72 + 32 + quad * 8]));
      short8 ah0 = __builtin_bit_cast(short8, *(const uint4v*)(&hist[hp][l15 * 72 + quad * 8]));
      short8 ah1 = __builtin_bit_cast(short8, *(const uint4v*)(&hist[hp][l15 * 72 + 32 + quad * 8]));
      f32x4 aX[4], aH[4];
      #pragma unroll
      for (int g = 0; g < 4; ++g) {
        aX[g] = (f32x4){bias_v[g], bias_v[g], bias_v[g], bias_v[g]};
        aX[g] = __builtin_amdgcn_mfma_f32_16x16x32_bf16(ax0, bx[g][0], aX[g], 0, 0, 0);
        aX[g] = __builtin_amdgcn_mfma_f32_16x16x32_bf16(ax1, bx[g][1], aX[g], 0, 0, 0);
        aH[g] = (f32x4){0.f, 0.f, 0.f, 0.f};
        aH[g] = __builtin_amdgcn_mfma_f32_16x16x32_bf16(ah0, bh[g][0], aH[g], 0, 0, 0);
        aH[g] = __builtin_amdgcn_mfma_f32_16x16x32_bf16(ah1, bh[g][1], aH[g], 0, 0, 0);
      }
      #pragma unroll
      for (int r = 0; r < 4; ++r) {
        float yi = aX[0][r] + aH[0][r];
        float yf = aX[1][r] + aH[1][r];
        float yg = aX[2][r] + aH[2][r];
        float yo = aX[3][r] + aH[3][r];
        float Fi = ex2(-yi);                 // e^-i (prescaled by log2e)
        float Ff = ex2(-yf);
        float Eg = ex2(yg);                  // e^{2g} (prescaled by 2log2e)
        float fg = __builtin_amdgcn_rcpf(1.0f + Ff);
        float igg = (Eg - 1.0f) * __builtin_amdgcn_rcpf((1.0f + Fi) * (Eg + 1.0f));
        cst[r] = fg * cst[r] + igg;
        float og = __builtin_amdgcn_rcpf(1.0f + ex2(-yo));
        float hh = og * tanh2(cst[r] * TL2E);
        hist[sl][(quad * 4 + r) * 72 + h0 + l15] = bfr(hh);
        if (c == 30 && sl == 6) {             // global step 246 = last real step
          int bglob = b0 + quad * 4 + r;
          hT[((size_t)dir * BB + bglob) * 64 + h0 + l15] = hh;
        }
      }
      lds_barrier();
    }
    uint4v dv[4];
    #pragma unroll
    for (int i = 0; i < 4; ++i) {
      int flat = i * 256 + tid;
      int sl = flat >> 7, wb = (flat >> 3) & 15, c8 = flat & 7;
      dv[i] = *(const uint4v*)(&hist[sl][wb * 72 + c8 * 8]);
    }
    #pragma unroll
    for (int i = 0; i < 4; ++i) {
      int flat = i * 256 + tid;
      int sl = flat >> 7, wb = (flat >> 3) & 15, c8 = flat & 7;
      int s = c * 8 + sl;
      if (s < TT) {
        int t = dir ? (TT - 1 - s) : s;
        *(uint4v*)(values + ((size_t)(b0 + wb) * TT + t) * D2 + dir * 64 + c8 * 8) = dv[i];
      }
    }
    if (c < 30) {
      #pragma unroll
      for (int k = 0; k < 8; ++k)
        *(uint2*)(&xls[1 - buf][k][bl * 72 + d4 * 4]) = xr[k];
      #pragma unroll
      for (int k = 0; k < 8; ++k) {
        int s2 = (c + 2) * 8 + k;
        if (s2 > TT - 1) s2 = TT - 1;
        int t2 = dir ? (TT - 1 - s2) : s2;
        xr[k] = *(const uint2*)(xrow + (size_t)t2 * 64);
      }
    }
    lds_barrier();
  }
}

// ---------------- K3b: q2 = h_n @ W2^T + W2_b ----------------
__global__ __launch_bounds__(128) void k_q2(const float* __restrict__ hT,
    const float* __restrict__ W2, const float* __restrict__ W2b,
    float* __restrict__ q2)
{
  int b = blockIdx.x;
  int tid = threadIdx.x;
  __shared__ float4 hn4[32];
  ((float*)hn4)[tid] = hT[(size_t)b * 128 + tid];
  __syncthreads();
  const float4* w4 = (const float4*)(W2 + (size_t)tid * 128);
  float a = W2b[tid];
  #pragma unroll
  for (int j = 0; j < 32; ++j) {
    float4 w = w4[j]; float4 h = hn4[j];
    a += w.x * h.x + w.y * h.y + w.z * h.z + w.w * h.w;
  }
  q2[(size_t)b * 128 + tid] = a;
}

// ---------------- K4: score via MFMA -> scoreT[b][n][t] bf16 (RAW scores) ----------------
__global__ __launch_bounds__(256) void k_score_m(const unsigned short* __restrict__ vbf,
    const unsigned short* __restrict__ W1bf, const float* __restrict__ W1b,
    const float* __restrict__ q2, const unsigned short* __restrict__ Vbf,
    const float* __restrict__ Vb, unsigned short* __restrict__ scoreT)
{
  int b = blockIdx.x, t0 = blockIdx.y * 64;
  int tid = threadIdx.x, w = tid >> 6, lane = tid & 63, l15 = lane & 15, quad = lane >> 4;
  __shared__ unsigned short us[64 * 136];
  __shared__ unsigned short sc2[64 * 213];
  const unsigned short* arow = vbf + ((size_t)b * TT + t0 + w * 16 + l15) * 128;
  short8 ax[4];
  #pragma unroll
  for (int ks = 0; ks < 4; ++ks)
    ax[ks] = __builtin_bit_cast(short8, *(const uint4v*)(arow + ks * 32 + quad * 8));
  #pragma unroll
  for (int nt = 0; nt < 8; ++nt) {
    int n = nt * 16 + l15;
    float base = W1b[n] + q2[(size_t)b * 128 + n];
    f32x4 acc = (f32x4){base, base, base, base};
    #pragma unroll
    for (int ks = 0; ks < 4; ++ks) {
      short8 bf = __builtin_bit_cast(short8,
          *(const uint4v*)(W1bf + (size_t)n * 128 + ks * 32 + quad * 8));
      acc = __builtin_amdgcn_mfma_f32_16x16x32_bf16(ax[ks], bf, acc, 0, 0, 0);
    }
    #pragma unroll
    for (int r = 0; r < 4; ++r)
      us[(w * 16 + quad * 4 + r) * 136 + nt * 16 + l15] = bfr(tanhff(acc[r]));
  }
  __syncthreads();
  short8 au[4];
  #pragma unroll
  for (int ks = 0; ks < 4; ++ks)
    au[ks] = __builtin_bit_cast(short8, *(const uint4v*)(&us[(w * 16 + l15) * 136 + ks * 32 + quad * 8]));
  for (int nt2 = 0; nt2 < 13; ++nt2) {
    int n = nt2 * 16 + l15;
    float b2 = (n < NTF) ? Vb[n] : 0.0f;
    f32x4 a2 = (f32x4){b2, b2, b2, b2};
    #pragma unroll
    for (int ks = 0; ks < 4; ++ks) {
      short8 bf = __builtin_bit_cast(short8,
          *(const uint4v*)(Vbf + (size_t)n * 128 + ks * 32 + quad * 8));
      a2 = __builtin_amdgcn_mfma_f32_16x16x32_bf16(au[ks], bf, a2, 0, 0, 0);
    }
    #pragma unroll
    for (int r = 0; r < 4; ++r) {
      int tl = w * 16 + quad * 4 + r;
      sc2[tl * 213 + n] = bfr(a2[r]);
    }
  }
  __syncthreads();
  int tg = tid & 3;
  #pragma unroll
  for (int pp = 0; pp < 4; ++pp) {
    int nrow = pp * 64 + (tid >> 2);
    if (nrow < NTF) {
      unsigned uu[8];
      #pragma unroll
      for (int k2 = 0; k2 < 8; ++k2) {
        unsigned lo = sc2[(tg * 16 + k2 * 2) * 213 + nrow];
        unsigned hi = sc2[(tg * 16 + k2 * 2 + 1) * 213 + nrow];
        uu[k2] = lo | (hi << 16);
      }
      size_t dst = ((size_t)b * 208 + nrow) * 256 + t0 + tg * 16;
      *(uint4v*)(scoreT + dst) = (uint4v){uu[0], uu[1], uu[2], uu[3]};
      *(uint4v*)(scoreT + dst + 8) = (uint4v){uu[4], uu[5], uu[6], uu[7]};
    }
  }
}

// ---------------- K6: FUSED softmax + context via MFMA -> ctxbf (bf16, [n][b][d]) --------
// Pass A computes per-row max + 1/sum (the former k_softmax) from raw scoreT; pass B
// applies exp2((a-m)*log2e) while building A-frags. Saves a full 108MB HBM pass + launch.
__global__ __launch_bounds__(256) void k_ctx_m(const unsigned short* __restrict__ vbf,
    const unsigned short* __restrict__ scoreT,
    unsigned short* __restrict__ ctxbf)
{
  int b = blockIdx.x;
  int tid = threadIdx.x, w = tid >> 6, lane = tid & 63, l15 = lane & 15, quad = lane >> 4;
  __shared__ __align__(16) unsigned short vt[128 * 264];  // [d][t]
  __shared__ float sm[208], sls[208];
  for (int flat = tid; flat < 247 * 64; flat += 256) {
    int t = flat >> 6, dp = flat & 63;
    unsigned v = *(const unsigned*)(vbf + ((size_t)b * TT + t) * D2 + dp * 2);
    vt[(dp * 2) * 264 + t] = (unsigned short)(v & 0xffffu);
    vt[(dp * 2 + 1) * 264 + t] = (unsigned short)(v >> 16);
  }
  for (int j = tid; j < 128 * 9; j += 256) {
    int d = j / 9, t = 247 + (j % 9);
    vt[d * 264 + t] = 0;
  }
  // ---- pass A: softmax stats ----
  {
    int nn = tid >> 2, tg = tid & 3;
    #pragma unroll
    for (int pp = 0; pp < 4; ++pp) {
      int n = pp * 64 + nn;
      if (n < 208) {
        const unsigned short* row = scoreT + ((size_t)b * 208 + n) * 256 + tg * 64;
        uint4v ld[8];
        #pragma unroll
        for (int i = 0; i < 8; ++i) ld[i] = *(const uint4v*)(row + i * 8);
        float m = -1e30f;
        #pragma unroll
        for (int i = 0; i < 8; ++i) {
          #pragma unroll
          for (int u = 0; u < 4; ++u) {
            unsigned xv = ld[i][u];
            int t0 = tg * 64 + i * 8 + u * 2;
            float a = __builtin_bit_cast(float, xv << 16);
            float cc = __builtin_bit_cast(float, xv & 0xffff0000u);
            if (t0 < TT) m = fmaxf(m, a);
            if (t0 + 1 < TT) m = fmaxf(m, cc);
          }
        }
        m = fmaxf(m, __shfl_xor(m, 1, 64));
        m = fmaxf(m, __shfl_xor(m, 2, 64));
        float s = 0.0f;
        #pragma unroll
        for (int i = 0; i < 8; ++i) {
          #pragma unroll
          for (int u = 0; u < 4; ++u) {
            unsigned xv = ld[i][u];
            int t0 = tg * 64 + i * 8 + u * 2;
            float a = __builtin_bit_cast(float, xv << 16);
            float cc = __builtin_bit_cast(float, xv & 0xffff0000u);
            if (t0 < TT) s += ex2((a - m) * L2E);
            if (t0 + 1 < TT) s += ex2((cc - m) * L2E);
          }
        }
        s += __shfl_xor(s, 1, 64);
        s += __shfl_xor(s, 2, 64);
        if (tg == 0) { sm[n] = m; sls[n] = __builtin_amdgcn_rcpf(s); }
      }
    }
  }
  __syncthreads();

  // ---- pass B: P = exp(score - m) on the fly -> PV MFMA ----
  const unsigned short* abase = scoreT + (size_t)b * 208 * 256;
  for (int mi = 0; mi < 4; ++mi) {
    int mt = w + 4 * mi;
    if (mt >= 13) continue;
    const unsigned short* arow = abase + (size_t)(mt * 16 + l15) * 256;
    float mrow = sm[mt * 16 + l15];
    short8 af[8];
    #pragma unroll
    for (int ks = 0; ks < 8; ++ks) {
      uint4v raw = *(const uint4v*)(arow + ks * 32 + quad * 8);
      uint4v pk;
      #pragma unroll
      for (int u = 0; u < 4; ++u) {
        unsigned xv = raw[u];
        int t0 = ks * 32 + quad * 8 + u * 2;
        float a = __builtin_bit_cast(float, xv << 16);
        float cc = __builtin_bit_cast(float, xv & 0xffff0000u);
        float pa = (t0 < TT) ? ex2((a - mrow) * L2E) : 0.0f;
        float pc = (t0 + 1 < TT) ? ex2((cc - mrow) * L2E) : 0.0f;
        pk[u] = (unsigned)bfr(pa) | ((unsigned)bfr(pc) << 16);
      }
      af[ks] = __builtin_bit_cast(short8, pk);
    }
    f32x4 acc[8];
    #pragma unroll
    for (int dt = 0; dt < 8; ++dt) {
      acc[dt] = (f32x4){0.f, 0.f, 0.f, 0.f};
      #pragma unroll
      for (int ks = 0; ks < 8; ++ks) {
        short8 bf = __builtin_bit_cast(short8,
            *(const uint4v*)(&vt[(dt * 16 + l15) * 264 + ks * 32 + quad * 8]));
        acc[dt] = __builtin_amdgcn_mfma_f32_16x16x32_bf16(af[ks], bf, acc[dt], 0, 0, 0);
      }
    }
    #pragma unroll
    for (int r = 0; r < 4; ++r) {
      int n = mt * 16 + quad * 4 + r;
      if (n < NTF) {
        float rs = sls[n];
        #pragma unroll
        for (int dt = 0; dt < 8; ++dt)
          ctxbf[((size_t)n * BB + b) * D2 + dt * 16 + l15] = bfr(acc[dt][r] * rs);
      }
    }
  }
}

// ---------------- K7: per-TF heads via MFMA (coalesced [n][b][d] ctx reads) ----------------
__global__ __launch_bounds__(256) void k_heads_m(const unsigned short* __restrict__ ctxbf,
    const unsigned short* __restrict__ f1bf, const float* __restrict__ fc1b,
    const float* __restrict__ fc2w, const float* __restrict__ fc2b,
    float* __restrict__ out)
{
  int n = blockIdx.x;
  int b0 = blockIdx.y * 128;
  int tid = threadIdx.x, w = tid >> 6, lane = tid & 63, l15 = lane & 15, quad = lane >> 4;
  // B-frags: fc1 rows for o = nt*16+l15 (resident)
  short8 bfr_[4][4];
  float f1bv[4], f2v[4];
  #pragma unroll
  for (int nt = 0; nt < 4; ++nt) {
    int o = nt * 16 + l15;
    #pragma unroll
    for (int ks = 0; ks < 4; ++ks)
      bfr_[nt][ks] = __builtin_bit_cast(short8,
          *(const uint4v*)(f1bf + ((size_t)n * 64 + o) * 128 + ks * 32 + quad * 8));
    f1bv[nt] = fc1b[n * 64 + o];
    f2v[nt] = fc2w[n * 64 + o];
  }
  float f2b = fc2b[n];
  #pragma unroll
  for (int mi = 0; mi < 2; ++mi) {
    int m16 = (w * 2 + mi) * 16;
    const unsigned short* arow = ctxbf + ((size_t)n * BB + (b0 + m16 + l15)) * 128;
    short8 af[4];
    #pragma unroll
    for (int ks = 0; ks < 4; ++ks)
      af[ks] = __builtin_bit_cast(short8, *(const uint4v*)(arow + ks * 32 + quad * 8));
    f32x4 acc[4];
    #pragma unroll
    for (int nt = 0; nt < 4; ++nt) {
      acc[nt] = (f32x4){0.f, 0.f, 0.f, 0.f};
      #pragma unroll
      for (int ks = 0; ks < 4; ++ks)
        acc[nt] = __builtin_amdgcn_mfma_f32_16x16x32_bf16(af[ks], bfr_[nt][ks], acc[nt], 0, 0, 0);
    }
    #pragma unroll
    for (int r = 0; r < 4; ++r) {
      float part = 0.0f;
      #pragma unroll
      for (int nt = 0; nt < 4; ++nt)
        part += fmaxf(acc[nt][r] + f1bv[nt], 0.0f) * f2v[nt];
      part += __shfl_xor(part, 1, 64);
      part += __shfl_xor(part, 2, 64);
      part += __shfl_xor(part, 4, 64);
      part += __shfl_xor(part, 8, 64);
      if (l15 == 0) {
        int bb = b0 + m16 + quad * 4 + r;
        out[(size_t)bb * NTF + n] = part + f2b;
      }
    }
  }
}

extern "C" void kernel_launch(void* const* d_in, const int* in_sizes, int n_in,
                              void* d_out, int out_size, void* d_ws, size_t ws_size,
                              hipStream_t stream)
{
  const float* x    = (const float*)d_in[0];
  const float* c0w  = (const float*)d_in[1];
  const float* c0b  = (const float*)d_in[2];
  const float* g0   = (const float*)d_in[3];
  const float* be0  = (const float*)d_in[4];
  const float* m0   = (const float*)d_in[5];
  const float* v0   = (const float*)d_in[6];
  const float* c1w  = (const float*)d_in[7];
  const float* c1b  = (const float*)d_in[8];
  const float* g1   = (const float*)d_in[9];
  const float* be1  = (const float*)d_in[10];
  const float* m1   = (const float*)d_in[11];
  const float* v1   = (const float*)d_in[12];
  const float* wihf = (const float*)d_in[13];
  const float* whhf = (const float*)d_in[14];
  const float* bihf = (const float*)d_in[15];
  const float* bhhf = (const float*)d_in[16];
  const float* wihb = (const float*)d_in[17];
  const float* whhb = (const float*)d_in[18];
  const float* bihb = (const float*)d_in[19];
  const float* bhhb = (const float*)d_in[20];
  const float* W1w  = (const float*)d_in[21];
  const float* W1b  = (const float*)d_in[22];
  const float* W2w  = (const float*)d_in[23];
  const float* W2b  = (const float*)d_in[24];
  const float* Vw   = (const float*)d_in[25];
  const float* Vb   = (const float*)d_in[26];
  const float* f1w  = (const float*)d_in[27];
  const float* f1b  = (const float*)d_in[28];
  const float* f2w  = (const float*)d_in[29];
  const float* f2b  = (const float*)d_in[30];

  float* ws = (float*)d_ws;
  unsigned short* scoreT = (unsigned short*)ws;            // [b][208][256] bf16 (raw scores)
  unsigned short* pbf  = (unsigned short*)ws;              // overlaps scoreT region (dead first)
  unsigned short* x2bf = (unsigned short*)(ws + 8323072);
  unsigned short* vbf  = (unsigned short*)(ws + 25292800);
  float* hT     = ws + 33387520;
  float* q2     = ws + 33453056;
  unsigned short* ctxbf = (unsigned short*)(ws + 33620992); // [n][b][d] bf16
  unsigned short* wbf0  = (unsigned short*)(ws + 46728192);
  unsigned short* wbf1r = (unsigned short*)(ws + 46729216);
  unsigned short* wihbf = (unsigned short*)(ws + 46745600);
  unsigned short* whhbf = (unsigned short*)(ws + 46761984);
  float* lbias          = ws + 46778368;
  unsigned short* W1bf  = (unsigned short*)(ws + 46778880);
  unsigned short* Vbf   = (unsigned short*)(ws + 46787072);
  unsigned short* f1bf  = (unsigned short*)(ws + 46800384); // 1,638,400 shorts
  float* out    = (float*)d_out;

  k_cvt<<<dim3(1600), 256, 0, stream>>>(c0w, c1w, wihf, whhf, wihb, whhb,
                                        bihf, bhhf, bihb, bhhb, W1w, Vw, f1w,
                                        wbf0, wbf1r, wihbf, whhbf, lbias, W1bf, Vbf, f1bf);
  k_conv0m<<<dim3(BB, 16), 256, 0, stream>>>(x, wbf0, c0b, g0, be0, m0, v0, pbf);
  k_conv1m<<<dim3(BB, 4), 256, 0, stream>>>(pbf, wbf1r, c1b, g1, be1, m1, v1, x2bf);
  k_lstm_m<<<dim3(BB / 16, 2), 256, 0, stream>>>(x2bf, wihbf, whhbf, lbias, vbf, hT);
  k_q2<<<dim3(BB), 128, 0, stream>>>(hT, W2w, W2b, q2);
  k_score_m<<<dim3(BB, 4), 256, 0, stream>>>(vbf, W1bf, W1b, q2, Vbf, Vb, scoreT);
  k_ctx_m<<<dim3(BB), 256, 0, stream>>>(vbf, scoreT, ctxbf);
  k_heads_m<<<dim3(NTF, 4), 256, 0, stream>>>(ctxbf, f1bf, f1b, f2w, f2b, out);
}

// Round 5
// 464.355 us; speedup vs baseline: 1.2886x; 1.0366x over previous
//
#include <hip/hip_runtime.h>
#include <math.h>

#define BB 512
#define LL 1024
#define EMB 4
#define CC 64
#define NTF 200
#define TT 247      // seq len after conv1
#define LP 254      // after pool
#define D2 128

typedef __attribute__((ext_vector_type(8))) short short8;
typedef __attribute__((ext_vector_type(4))) float f32x4;
typedef __attribute__((ext_vector_type(4))) unsigned int uint4v;

#define L2E  1.4426950408889634f   // log2(e)
#define TL2E 2.8853900817779268f   // 2*log2(e)

// exp2 native (v_exp_f32 computes 2^x)
__device__ __forceinline__ float ex2(float x) {
  return __builtin_amdgcn_exp2f(x);
}
// y is the preactivation already scaled by 2*log2(e)
__device__ __forceinline__ float tanh2(float y) {
  return 1.0f - 2.0f * __builtin_amdgcn_rcpf(ex2(y) + 1.0f);
}

// LDS-only barrier: 0xC07F = vmcnt(63)|expcnt(7)|lgkmcnt(0).
__device__ __forceinline__ void lds_barrier() {
  __builtin_amdgcn_s_waitcnt(0xC07F);
  __builtin_amdgcn_s_barrier();
}

// f32 -> bf16 round-to-nearest-even (finite inputs)
__device__ __forceinline__ unsigned short bfr(float f) {
  unsigned u = __builtin_bit_cast(unsigned, f);
  u += 0x7fffu + ((u >> 16) & 1u);
  return (unsigned short)(u >> 16);
}

// ---------------- K0: weight conversions ----------------
// grid 1600*256; f1bf converted 4/thread (vectorized). wbf1r is w1 REORDERED to [co][k][ci].
// LSTM gate weights/biases PRE-SCALED by log2(e) (2*log2e for g gate) -> native exp2 gates.
__global__ __launch_bounds__(256) void k_cvt(const float* __restrict__ w0,
    const float* __restrict__ w1,
    const float* __restrict__ wihf, const float* __restrict__ whhf,
    const float* __restrict__ wihb, const float* __restrict__ whhb,
    const float* __restrict__ bihf, const float* __restrict__ bhhf,
    const float* __restrict__ bihb, const float* __restrict__ bhhb,
    const float* __restrict__ W1w, const float* __restrict__ Vw,
    const float* __restrict__ f1w,
    unsigned short* __restrict__ wbf0, unsigned short* __restrict__ wbf1r,
    unsigned short* __restrict__ wihbf, unsigned short* __restrict__ whhbf,
    float* __restrict__ lbias,
    unsigned short* __restrict__ W1bf, unsigned short* __restrict__ Vbf,
    unsigned short* __restrict__ f1bf)
{
  int i = blockIdx.x * 256 + threadIdx.x;
  if (i < 2048) wbf0[i] = bfr(w0[i]);
  if (i < 32768) {                           // dst [co][k][ci] <- src [co][ci][k]
    int co = i >> 9, k = (i >> 6) & 7, ci = i & 63;
    wbf1r[i] = bfr(w1[co * 512 + ci * 8 + k]);
  }
  if (i < 16384) {
    float s = ((i >> 12) == 2) ? TL2E : L2E;  // gate = row>>6 = i>>12
    wihbf[i] = bfr(wihf[i] * s);
    wihbf[16384 + i] = bfr(wihb[i] * s);
    whhbf[i] = bfr(whhf[i] * s);
    whhbf[16384 + i] = bfr(whhb[i] * s);
    W1bf[i] = bfr(W1w[i]);                    // attention W1: unscaled
  }
  if (i < 26624) {                           // Vbf padded to 208 rows
    int row = i >> 7;
    Vbf[i] = (row < NTF) ? bfr(Vw[i]) : (unsigned short)0;
  }
  if (i < 256) {
    float s = ((i >> 6) == 2) ? TL2E : L2E;
    lbias[i] = (bihf[i] + bhhf[i]) * s;
    lbias[256 + i] = (bihb[i] + bhhb[i]) * s;
  }
  {
    int i4 = i * 4;
    if (i4 < 1638400) {                      // [n][o][k] flat, 4 elems/thread
      float4 v = *(const float4*)(f1w + i4);
      f1bf[i4 + 0] = bfr(v.x);
      f1bf[i4 + 1] = bfr(v.y);
      f1bf[i4 + 2] = bfr(v.z);
      f1bf[i4 + 3] = bfr(v.w);
    }
  }
}

// ---------------- K1: conv0 + BN + ReLU + maxpool(4), MFMA -> pbf (bf16) ----------------
// 4 l-tiles per block (grid BB x 4); B-frags hoisted out of the tile loop.
__global__ __launch_bounds__(256) void k_conv0m(const float* __restrict__ x,
    const unsigned short* __restrict__ wbf0,
    const float* __restrict__ b0, const float* __restrict__ g0,
    const float* __restrict__ be0, const float* __restrict__ m0,
    const float* __restrict__ v0, unsigned short* __restrict__ pbf)
{
  int b = blockIdx.x;
  int tid = threadIdx.x;
  __shared__ float xs[71 * 4];
  __shared__ float sc[64], sb[64];
  if (tid < 64) {
    float s = g0[tid] * rsqrtf(v0[tid] + 1e-5f);
    sc[tid] = s;
    sb[tid] = (b0[tid] - m0[tid]) * s + be0[tid];
  }
  int w = tid >> 6, lane = tid & 63, nl = lane & 15, quad = lane >> 4;
  short8 bfb[4];
  #pragma unroll
  for (int nt = 0; nt < 4; ++nt)
    bfb[nt] = __builtin_bit_cast(short8,
        *(const uint4v*)(wbf0 + ((nt * 16 + nl) * 32 + quad * 8)));
  for (int li = 0; li < 4; ++li) {
    int l0 = blockIdx.y * 256 + li * 64;
    for (int j = tid; j < 71; j += 256) {
      int l = l0 + j;
      float4 xv = (l < LL) ? *(const float4*)(x + ((size_t)b * LL + l) * EMB)
                           : make_float4(0.f, 0.f, 0.f, 0.f);
      *(float4*)(xs + j * 4) = xv;
    }
    __syncthreads();
    const float* ap = xs + (w * 16 + nl) * 4 + quad;
    short8 af;
    #pragma unroll
    for (int j = 0; j < 8; ++j) af[j] = (short)bfr(ap[j * 4]);
    f32x4 acc[4];
    #pragma unroll
    for (int nt = 0; nt < 4; ++nt) {
      acc[nt] = (f32x4){0.f, 0.f, 0.f, 0.f};
      acc[nt] = __builtin_amdgcn_mfma_f32_16x16x32_bf16(af, bfb[nt], acc[nt], 0, 0, 0);
    }
    int t = (l0 >> 2) + w * 4 + quad;
    if (t < LP) {
      #pragma unroll
      for (int nt = 0; nt < 4; ++nt) {
        int c = nt * 16 + nl;
        float scc = sc[c], sbc = sb[c];
        float mx = -1e30f;
        #pragma unroll
        for (int r = 0; r < 4; ++r) mx = fmaxf(mx, acc[nt][r] * scc + sbc);
        pbf[((size_t)b * LP + t) * CC + c] = bfr(fmaxf(mx, 0.0f));
      }
    }
    __syncthreads();
  }
}

// ---------------- K2: conv1 as 8 shifted GEMMs (bf16 p, reordered weights) ----------------
__global__ __launch_bounds__(256) void k_conv1m(const unsigned short* __restrict__ pbf,
    const unsigned short* __restrict__ wbf1r,
    const float* __restrict__ b1, const float* __restrict__ g1,
    const float* __restrict__ be1, const float* __restrict__ m1,
    const float* __restrict__ v1, unsigned short* __restrict__ x2bf)
{
  int b = blockIdx.x, t0 = blockIdx.y * 64;
  __shared__ __align__(16) unsigned short ps[71 * 72];
  __shared__ float sc[64], sb[64];
  int tid = threadIdx.x;
  for (int j = tid; j < 71 * 32; j += 256) {
    int tl = j >> 5, cu = j & 31;
    int t = t0 + tl;
    unsigned v = (t < LP) ? *(const unsigned*)(pbf + ((size_t)b * LP + t) * CC + cu * 2) : 0u;
    *(unsigned*)(&ps[tl * 72 + cu * 2]) = v;
  }
  if (tid < 64) {
    float s = g1[tid] * rsqrtf(v1[tid] + 1e-5f);
    sc[tid] = s;
    sb[tid] = (b1[tid] - m1[tid]) * s + be1[tid];
  }
  __syncthreads();
  int w = tid >> 6, lane = tid & 63, nl = lane & 15, quad = lane >> 4;
  int tlb = w * 16 + nl;
  f32x4 acc[4];
  #pragma unroll
  for (int nt = 0; nt < 4; ++nt) acc[nt] = (f32x4){0.f, 0.f, 0.f, 0.f};
  #pragma unroll
  for (int k8 = 0; k8 < 8; ++k8) {
    short8 af0 = __builtin_bit_cast(short8,
        *(const uint4v*)(&ps[(tlb + k8) * 72 + 0 + quad * 8]));
    short8 af1 = __builtin_bit_cast(short8,
        *(const uint4v*)(&ps[(tlb + k8) * 72 + 32 + quad * 8]));
    #pragma unroll
    for (int nt = 0; nt < 4; ++nt) {
      int co = nt * 16 + nl;
      short8 bf0 = __builtin_bit_cast(short8,
          *(const uint4v*)(wbf1r + (size_t)co * 512 + k8 * 64 + 0 + quad * 8));
      short8 bf1 = __builtin_bit_cast(short8,
          *(const uint4v*)(wbf1r + (size_t)co * 512 + k8 * 64 + 32 + quad * 8));
      acc[nt] = __builtin_amdgcn_mfma_f32_16x16x32_bf16(af0, bf0, acc[nt], 0, 0, 0);
      acc[nt] = __builtin_amdgcn_mfma_f32_16x16x32_bf16(af1, bf1, acc[nt], 0, 0, 0);
    }
  }
  #pragma unroll
  for (int nt = 0; nt < 4; ++nt) {
    int c = nt * 16 + nl;
    float scc = sc[c], sbc = sb[c];
    #pragma unroll
    for (int r = 0; r < 4; ++r) {
      int t = t0 + w * 16 + quad * 4 + r;
      if (t < TT)
        x2bf[((size_t)b * TT + t) * CC + c] = bfr(fmaxf(acc[nt][r] * scc + sbc, 0.0f));
    }
  }
}

// ---------------- K3: bi-LSTM via MFMA (R0 structure; lean issue stream) ----------------
// Per gate: bias-init accumulator, 4 chained MFMAs (x then h) -- no aX+aH adds.
// Gate math: exp2-prescaled; i*tanh(g) AND o*tanh(c) each fused to a single rcp.
__global__ __launch_bounds__(256) void k_lstm_m(const unsigned short* __restrict__ x2bf,
    const unsigned short* __restrict__ wihbf, const unsigned short* __restrict__ whhbf,
    const float* __restrict__ lbias,
    unsigned short* __restrict__ values, float* __restrict__ hT)
{
  int b0 = blockIdx.x * 16;
  int dir = blockIdx.y;
  int tid = threadIdx.x;
  int w = tid >> 6, lane = tid & 63, l15 = lane & 15, quad = lane >> 4;
  int h0 = w * 16;
  const unsigned short* wih = wihbf + dir * 16384;
  const unsigned short* whh = whhbf + dir * 16384;

  short8 bx[4][2], bh[4][2];
  float bias_v[4];
  #pragma unroll
  for (int g = 0; g < 4; ++g) {
    int row = g * 64 + h0 + l15;
    #pragma unroll
    for (int k = 0; k < 2; ++k) {
      bx[g][k] = __builtin_bit_cast(short8, *(const uint4v*)(wih + row * 64 + k * 32 + quad * 8));
      bh[g][k] = __builtin_bit_cast(short8, *(const uint4v*)(whh + row * 64 + k * 32 + quad * 8));
    }
    bias_v[g] = lbias[dir * 256 + g * 64 + h0 + l15];
  }

  __shared__ __align__(16) unsigned short xls[2][8][16 * 72];
  __shared__ __align__(16) unsigned short hist[8][16 * 72];
  for (int j = tid; j < 16 * 72; j += 256) hist[7][j] = 0;  // h_{-1} = 0

  int bl = tid >> 4, d4 = tid & 15;
  const unsigned short* xrow = x2bf + ((size_t)(b0 + bl) * TT) * 64 + d4 * 4;

  uint2 xr[8];
  #pragma unroll
  for (int k = 0; k < 8; ++k) {               // chunk 0
    int t = dir ? (TT - 1 - k) : k;
    xr[k] = *(const uint2*)(xrow + (size_t)t * 64);
  }
  #pragma unroll
  for (int k = 0; k < 8; ++k)
    *(uint2*)(&xls[0][k][bl * 72 + d4 * 4]) = xr[k];
  #pragma unroll
  for (int k = 0; k < 8; ++k) {               // chunk 1
    int s = 8 + k;
    int t = dir ? (TT - 1 - s) : s;
    xr[k] = *(const uint2*)(xrow + (size_t)t * 64);
  }
  __syncthreads();

  float cst[4] = {0.f, 0.f, 0.f, 0.f};
  for (int c = 0; c < 31; ++c) {
    int buf = c & 1;
    #pragma unroll
    for (int sl = 0; sl < 8; ++sl) {
      int hp = (sl + 7) & 7;
      short8 ax0 = __builtin_bit_cast(short8, *(const uint4v*)(&xls[buf][sl][l15 * 72 + quad * 8]));
      short8 ax1 = __builtin_bit_cast(short8, *(const uint4v*)(&xls[buf][sl][l15 * 72 + 32 + quad * 8]));
      short8 ah0 = __builtin_bit_cast(short8, *(const uint4v*)(&hist[hp][l15 * 72 + quad * 8]));
      short8 ah1 = __builtin_bit_cast(short8, *(const uint4v*)(&hist[hp][l15 * 72 + 32 + quad * 8]));
      f32x4 acc[4];
      #pragma unroll
      for (int g = 0; g < 4; ++g) {
        acc[g] = (f32x4){bias_v[g], bias_v[g], bias_v[g], bias_v[g]};
        acc[g] = __builtin_amdgcn_mfma_f32_16x16x32_bf16(ax0, bx[g][0], acc[g], 0, 0, 0);
        acc[g] = __builtin_amdgcn_mfma_f32_16x16x32_bf16(ax1, bx[g][1], acc[g], 0, 0, 0);
        acc[g] = __builtin_amdgcn_mfma_f32_16x16x32_bf16(ah0, bh[g][0], acc[g], 0, 0, 0);
        acc[g] = __builtin_amdgcn_mfma_f32_16x16x32_bf16(ah1, bh[g][1], acc[g], 0, 0, 0);
      }
      #pragma unroll
      for (int r = 0; r < 4; ++r) {
        float Fi = ex2(-acc[0][r]);          // e^-i (prescaled by log2e)
        float Ff = ex2(-acc[1][r]);
        float Eg = ex2(acc[2][r]);           // e^{2g} (prescaled by 2log2e)
        float fg = __builtin_amdgcn_rcpf(1.0f + Ff);
        float igg = (Eg - 1.0f) * __builtin_amdgcn_rcpf((1.0f + Fi) * (Eg + 1.0f));
        cst[r] = fg * cst[r] + igg;
        float Fo = ex2(-acc[3][r]);
        float Ec = ex2(cst[r] * TL2E);       // e^{2c}
        float hh = (Ec - 1.0f) * __builtin_amdgcn_rcpf((1.0f + Fo) * (Ec + 1.0f));
        hist[sl][(quad * 4 + r) * 72 + h0 + l15] = bfr(hh);
        if (c == 30 && sl == 6) {             // global step 246 = last real step
          int bglob = b0 + quad * 4 + r;
          hT[((size_t)dir * BB + bglob) * 64 + h0 + l15] = hh;
        }
      }
      lds_barrier();
    }
    uint4v dv[4];
    #pragma unroll
    for (int i = 0; i < 4; ++i) {
      int flat = i * 256 + tid;
      int sl = flat >> 7, wb = (flat >> 3) & 15, c8 = flat & 7;
      dv[i] = *(const uint4v*)(&hist[sl][wb * 72 + c8 * 8]);
    }
    #pragma unroll
    for (int i = 0; i < 4; ++i) {
      int flat = i * 256 + tid;
      int sl = flat >> 7, wb = (flat >> 3) & 15, c8 = flat & 7;
      int s = c * 8 + sl;
      if (s < TT) {
        int t = dir ? (TT - 1 - s) : s;
        *(uint4v*)(values + ((size_t)(b0 + wb) * TT + t) * D2 + dir * 64 + c8 * 8) = dv[i];
      }
    }
    if (c < 30) {
      #pragma unroll
      for (int k = 0; k < 8; ++k)
        *(uint2*)(&xls[1 - buf][k][bl * 72 + d4 * 4]) = xr[k];
      #pragma unroll
      for (int k = 0; k < 8; ++k) {
        int s2 = (c + 2) * 8 + k;
        if (s2 > TT - 1) s2 = TT - 1;
        int t2 = dir ? (TT - 1 - s2) : s2;
        xr[k] = *(const uint2*)(xrow + (size_t)t2 * 64);
      }
    }
    lds_barrier();
  }
}

// ---------------- K3b: q2 = h_n @ W2^T + W2_b ----------------
__global__ __launch_bounds__(128) void k_q2(const float* __restrict__ hT,
    const float* __restrict__ W2, const float* __restrict__ W2b,
    float* __restrict__ q2)
{
  int b = blockIdx.x;
  int tid = threadIdx.x;
  __shared__ float4 hn4[32];
  ((float*)hn4)[tid] = hT[(size_t)b * 128 + tid];
  __syncthreads();
  const float4* w4 = (const float4*)(W2 + (size_t)tid * 128);
  float a = W2b[tid];
  #pragma unroll
  for (int j = 0; j < 32; ++j) {
    float4 w = w4[j]; float4 h = hn4[j];
    a += w.x * h.x + w.y * h.y + w.z * h.z + w.w * h.w;
  }
  q2[(size_t)b * 128 + tid] = a;
}

// ---------------- K4: score via MFMA -> scoreT[b][n][t] bf16 + softmax PARTIALS ----------
// Each block owns one 64-t tile; while the bf16 scores are still in registers (uu[8]) it
// computes the per-tile (max, sum) for each n and writes tiny [b][NTF][4] partials.
__global__ __launch_bounds__(256) void k_score_m(const unsigned short* __restrict__ vbf,
    const unsigned short* __restrict__ W1bf, const float* __restrict__ W1b,
    const float* __restrict__ q2, const unsigned short* __restrict__ Vbf,
    const float* __restrict__ Vb, unsigned short* __restrict__ scoreT,
    float* __restrict__ pmax, float* __restrict__ psum)
{
  int b = blockIdx.x, t0 = blockIdx.y * 64;
  int tid = threadIdx.x, w = tid >> 6, lane = tid & 63, l15 = lane & 15, quad = lane >> 4;
  __shared__ unsigned short us[64 * 136];
  __shared__ unsigned short sc2[64 * 213];
  const unsigned short* arow = vbf + ((size_t)b * TT + t0 + w * 16 + l15) * 128;
  short8 ax[4];
  #pragma unroll
  for (int ks = 0; ks < 4; ++ks)
    ax[ks] = __builtin_bit_cast(short8, *(const uint4v*)(arow + ks * 32 + quad * 8));
  #pragma unroll
  for (int nt = 0; nt < 8; ++nt) {
    int n = nt * 16 + l15;
    float base = W1b[n] + q2[(size_t)b * 128 + n];
    f32x4 acc = (f32x4){base, base, base, base};
    #pragma unroll
    for (int ks = 0; ks < 4; ++ks) {
      short8 bf = __builtin_bit_cast(short8,
          *(const uint4v*)(W1bf + (size_t)n * 128 + ks * 32 + quad * 8));
      acc = __builtin_amdgcn_mfma_f32_16x16x32_bf16(ax[ks], bf, acc, 0, 0, 0);
    }
    #pragma unroll
    for (int r = 0; r < 4; ++r)
      us[(w * 16 + quad * 4 + r) * 136 + nt * 16 + l15] = bfr(tanh2(acc[r] * TL2E));
  }
  __syncthreads();
  short8 au[4];
  #pragma unroll
  for (int ks = 0; ks < 4; ++ks)
    au[ks] = __builtin_bit_cast(short8, *(const uint4v*)(&us[(w * 16 + l15) * 136 + ks * 32 + quad * 8]));
  for (int nt2 = 0; nt2 < 13; ++nt2) {
    int n = nt2 * 16 + l15;
    float b2 = (n < NTF) ? Vb[n] : 0.0f;
    f32x4 a2 = (f32x4){b2, b2, b2, b2};
    #pragma unroll
    for (int ks = 0; ks < 4; ++ks) {
      short8 bf = __builtin_bit_cast(short8,
          *(const uint4v*)(Vbf + (size_t)n * 128 + ks * 32 + quad * 8));
      a2 = __builtin_amdgcn_mfma_f32_16x16x32_bf16(au[ks], bf, a2, 0, 0, 0);
    }
    #pragma unroll
    for (int r = 0; r < 4; ++r) {
      int tl = w * 16 + quad * 4 + r;
      sc2[tl * 213 + n] = bfr(a2[r]);
    }
  }
  __syncthreads();
  int tg = tid & 3;
  #pragma unroll
  for (int pp = 0; pp < 4; ++pp) {
    int nrow = pp * 64 + (tid >> 2);
    if (nrow < NTF) {
      unsigned uu[8];
      #pragma unroll
      for (int k2 = 0; k2 < 8; ++k2) {
        unsigned lo = sc2[(tg * 16 + k2 * 2) * 213 + nrow];
        unsigned hi = sc2[(tg * 16 + k2 * 2 + 1) * 213 + nrow];
        uu[k2] = lo | (hi << 16);
      }
      size_t dst = ((size_t)b * 208 + nrow) * 256 + t0 + tg * 16;
      *(uint4v*)(scoreT + dst) = (uint4v){uu[0], uu[1], uu[2], uu[3]};
      *(uint4v*)(scoreT + dst + 8) = (uint4v){uu[4], uu[5], uu[6], uu[7]};
      // softmax partials over this 16-t slice (values already bf16-rounded)
      float pm = -1e30f;
      #pragma unroll
      for (int k2 = 0; k2 < 8; ++k2) {
        unsigned xv = uu[k2];
        int t = t0 + tg * 16 + k2 * 2;
        float a = __builtin_bit_cast(float, xv << 16);
        float c2 = __builtin_bit_cast(float, xv & 0xffff0000u);
        if (t < TT) pm = fmaxf(pm, a);
        if (t + 1 < TT) pm = fmaxf(pm, c2);
      }
      float ps = 0.0f;
      #pragma unroll
      for (int k2 = 0; k2 < 8; ++k2) {
        unsigned xv = uu[k2];
        int t = t0 + tg * 16 + k2 * 2;
        float a = __builtin_bit_cast(float, xv << 16);
        float c2 = __builtin_bit_cast(float, xv & 0xffff0000u);
        if (t < TT) ps += ex2((a - pm) * L2E);
        if (t + 1 < TT) ps += ex2((c2 - pm) * L2E);
      }
      // combine 4 tg lanes (same nrow) -> tile partial
      float om = __shfl_xor(pm, 1, 64), os = __shfl_xor(ps, 1, 64);
      float nm = fmaxf(pm, om);
      ps = ps * ex2((pm - nm) * L2E) + os * ex2((om - nm) * L2E);
      pm = nm;
      om = __shfl_xor(pm, 2, 64); os = __shfl_xor(ps, 2, 64);
      nm = fmaxf(pm, om);
      ps = ps * ex2((pm - nm) * L2E) + os * ex2((om - nm) * L2E);
      pm = nm;
      if (tg == 0) {
        pmax[((size_t)b * NTF + nrow) * 4 + blockIdx.y] = pm;
        psum[((size_t)b * NTF + nrow) * 4 + blockIdx.y] = ps;
      }
    }
  }
}

// ---------------- K6: softmax(from partials) + context via MFMA -> ctxbf ([n][b][d]) ------
__global__ __launch_bounds__(256) void k_ctx_m(const unsigned short* __restrict__ vbf,
    const unsigned short* __restrict__ scoreT,
    const float* __restrict__ pmax, const float* __restrict__ psum,
    unsigned short* __restrict__ ctxbf)
{
  int b = blockIdx.x;
  int tid = threadIdx.x, w = tid >> 6, lane = tid & 63, l15 = lane & 15, quad = lane >> 4;
  __shared__ __align__(16) unsigned short vt[128 * 264];  // [d][t]
  __shared__ float sm[208], sls[208];
  for (int flat = tid; flat < 247 * 64; flat += 256) {
    int t = flat >> 6, dp = flat & 63;
    unsigned v = *(const unsigned*)(vbf + ((size_t)b * TT + t) * D2 + dp * 2);
    vt[(dp * 2) * 264 + t] = (unsigned short)(v & 0xffffu);
    vt[(dp * 2 + 1) * 264 + t] = (unsigned short)(v >> 16);
  }
  for (int j = tid; j < 128 * 9; j += 256) {
    int d = j / 9, t = 247 + (j % 9);
    vt[d * 264 + t] = 0;
  }
  // combine the 4 per-tile partials into (max, 1/sum) per row
  for (int j = tid; j < 208; j += 256) {
    if (j < NTF) {
      const float* pmr = pmax + ((size_t)b * NTF + j) * 4;
      const float* psr = psum + ((size_t)b * NTF + j) * 4;
      float m0 = pmr[0], m1 = pmr[1], m2 = pmr[2], m3 = pmr[3];
      float mm = fmaxf(fmaxf(m0, m1), fmaxf(m2, m3));
      float s = psr[0] * ex2((m0 - mm) * L2E) + psr[1] * ex2((m1 - mm) * L2E)
              + psr[2] * ex2((m2 - mm) * L2E) + psr[3] * ex2((m3 - mm) * L2E);
      sm[j] = mm;
      sls[j] = __builtin_amdgcn_rcpf(s);
    } else {
      sm[j] = 1e30f;   // forces P=0 for pad rows
      sls[j] = 0.0f;
    }
  }
  __syncthreads();

  // P = exp(score - m) on the fly -> PV MFMA
  const unsigned short* abase = scoreT + (size_t)b * 208 * 256;
  for (int mi = 0; mi < 4; ++mi) {
    int mt = w + 4 * mi;
    if (mt >= 13) continue;
    const unsigned short* arow = abase + (size_t)(mt * 16 + l15) * 256;
    float mrow = sm[mt * 16 + l15];
    short8 af[8];
    #pragma unroll
    for (int ks = 0; ks < 8; ++ks) {
      uint4v raw = *(const uint4v*)(arow + ks * 32 + quad * 8);
      uint4v pk;
      #pragma unroll
      for (int u = 0; u < 4; ++u) {
        unsigned xv = raw[u];
        int t0 = ks * 32 + quad * 8 + u * 2;
        float a = __builtin_bit_cast(float, xv << 16);
        float cc = __builtin_bit_cast(float, xv & 0xffff0000u);
        float pa = (t0 < TT) ? ex2((a - mrow) * L2E) : 0.0f;
        float pc = (t0 + 1 < TT) ? ex2((cc - mrow) * L2E) : 0.0f;
        pk[u] = (unsigned)bfr(pa) | ((unsigned)bfr(pc) << 16);
      }
      af[ks] = __builtin_bit_cast(short8, pk);
    }
    f32x4 acc[8];
    #pragma unroll
    for (int dt = 0; dt < 8; ++dt) {
      acc[dt] = (f32x4){0.f, 0.f, 0.f, 0.f};
      #pragma unroll
      for (int ks = 0; ks < 8; ++ks) {
        short8 bf = __builtin_bit_cast(short8,
            *(const uint4v*)(&vt[(dt * 16 + l15) * 264 + ks * 32 + quad * 8]));
        acc[dt] = __builtin_amdgcn_mfma_f32_16x16x32_bf16(af[ks], bf, acc[dt], 0, 0, 0);
      }
    }
    #pragma unroll
    for (int r = 0; r < 4; ++r) {
      int n = mt * 16 + quad * 4 + r;
      if (n < NTF) {
        float rs = sls[n];
        #pragma unroll
        for (int dt = 0; dt < 8; ++dt)
          ctxbf[((size_t)n * BB + b) * D2 + dt * 16 + l15] = bfr(acc[dt][r] * rs);
      }
    }
  }
}

// ---------------- K7: per-TF heads via MFMA (coalesced [n][b][d] ctx reads) ----------------
__global__ __launch_bounds__(256) void k_heads_m(const unsigned short* __restrict__ ctxbf,
    const unsigned short* __restrict__ f1bf, const float* __restrict__ fc1b,
    const float* __restrict__ fc2w, const float* __restrict__ fc2b,
    float* __restrict__ out)
{
  int n = blockIdx.x;
  int b0 = blockIdx.y * 128;
  int tid = threadIdx.x, w = tid >> 6, lane = tid & 63, l15 = lane & 15, quad = lane >> 4;
  // B-frags: fc1 rows for o = nt*16+l15 (resident)
  short8 bfr_[4][4];
  float f1bv[4], f2v[4];
  #pragma unroll
  for (int nt = 0; nt < 4; ++nt) {
    int o = nt * 16 + l15;
    #pragma unroll
    for (int ks = 0; ks < 4; ++ks)
      bfr_[nt][ks] = __builtin_bit_cast(short8,
          *(const uint4v*)(f1bf + ((size_t)n * 64 + o) * 128 + ks * 32 + quad * 8));
    f1bv[nt] = fc1b[n * 64 + o];
    f2v[nt] = fc2w[n * 64 + o];
  }
  float f2b = fc2b[n];
  #pragma unroll
  for (int mi = 0; mi < 2; ++mi) {
    int m16 = (w * 2 + mi) * 16;
    const unsigned short* arow = ctxbf + ((size_t)n * BB + (b0 + m16 + l15)) * 128;
    short8 af[4];
    #pragma unroll
    for (int ks = 0; ks < 4; ++ks)
      af[ks] = __builtin_bit_cast(short8, *(const uint4v*)(arow + ks * 32 + quad * 8));
    f32x4 acc[4];
    #pragma unroll
    for (int nt = 0; nt < 4; ++nt) {
      acc[nt] = (f32x4){0.f, 0.f, 0.f, 0.f};
      #pragma unroll
      for (int ks = 0; ks < 4; ++ks)
        acc[nt] = __builtin_amdgcn_mfma_f32_16x16x32_bf16(af[ks], bfr_[nt][ks], acc[nt], 0, 0, 0);
    }
    #pragma unroll
    for (int r = 0; r < 4; ++r) {
      float part = 0.0f;
      #pragma unroll
      for (int nt = 0; nt < 4; ++nt)
        part += fmaxf(acc[nt][r] + f1bv[nt], 0.0f) * f2v[nt];
      part += __shfl_xor(part, 1, 64);
      part += __shfl_xor(part, 2, 64);
      part += __shfl_xor(part, 4, 64);
      part += __shfl_xor(part, 8, 64);
      if (l15 == 0) {
        int bb = b0 + m16 + quad * 4 + r;
        out[(size_t)bb * NTF + n] = part + f2b;
      }
    }
  }
}

extern "C" void kernel_launch(void* const* d_in, const int* in_sizes, int n_in,
                              void* d_out, int out_size, void* d_ws, size_t ws_size,
                              hipStream_t stream)
{
  const float* x    = (const float*)d_in[0];
  const float* c0w  = (const float*)d_in[1];
  const float* c0b  = (const float*)d_in[2];
  const float* g0   = (const float*)d_in[3];
  const float* be0  = (const float*)d_in[4];
  const float* m0   = (const float*)d_in[5];
  const float* v0   = (const float*)d_in[6];
  const float* c1w  = (const float*)d_in[7];
  const float* c1b  = (const float*)d_in[8];
  const float* g1   = (const float*)d_in[9];
  const float* be1  = (const float*)d_in[10];
  const float* m1   = (const float*)d_in[11];
  const float* v1   = (const float*)d_in[12];
  const float* wihf = (const float*)d_in[13];
  const float* whhf = (const float*)d_in[14];
  const float* bihf = (const float*)d_in[15];
  const float* bhhf = (const float*)d_in[16];
  const float* wihb = (const float*)d_in[17];
  const float* whhb = (const float*)d_in[18];
  const float* bihb = (const float*)d_in[19];
  const float* bhhb = (const float*)d_in[20];
  const float* W1w  = (const float*)d_in[21];
  const float* W1b  = (const float*)d_in[22];
  const float* W2w  = (const float*)d_in[23];
  const float* W2b  = (const float*)d_in[24];
  const float* Vw   = (const float*)d_in[25];
  const float* Vb   = (const float*)d_in[26];
  const float* f1w  = (const float*)d_in[27];
  const float* f1b  = (const float*)d_in[28];
  const float* f2w  = (const float*)d_in[29];
  const float* f2b  = (const float*)d_in[30];

  float* ws = (float*)d_ws;
  unsigned short* scoreT = (unsigned short*)ws;            // [b][208][256] bf16 = [0, 13,631,488) floats
  unsigned short* pbf  = (unsigned short*)ws;              // overlaps scoreT region (dead first)
  unsigned short* x2bf = (unsigned short*)(ws + 8323072);  // [8,323,072, 12,369,920) floats (dead after lstm)
  float* pmax   = ws + 14000000;                           // [b][NTF][4] = 409,600 floats (AFTER scoreT end!)
  float* psum   = ws + 14500000;                           // 409,600 floats, ends 14,909,600 < vbf 25,292,800
  unsigned short* vbf  = (unsigned short*)(ws + 25292800);
  float* hT     = ws + 33387520;
  float* q2     = ws + 33453056;
  unsigned short* ctxbf = (unsigned short*)(ws + 33620992); // [n][b][d] bf16
  unsigned short* wbf0  = (unsigned short*)(ws + 46728192);
  unsigned short* wbf1r = (unsigned short*)(ws + 46729216);
  unsigned short* wihbf = (unsigned short*)(ws + 46745600);
  unsigned short* whhbf = (unsigned short*)(ws + 46761984);
  float* lbias          = ws + 46778368;
  unsigned short* W1bf  = (unsigned short*)(ws + 46778880);
  unsigned short* Vbf   = (unsigned short*)(ws + 46787072);
  unsigned short* f1bf  = (unsigned short*)(ws + 46800384); // 1,638,400 shorts
  float* out    = (float*)d_out;

  k_cvt<<<dim3(1600), 256, 0, stream>>>(c0w, c1w, wihf, whhf, wihb, whhb,
                                        bihf, bhhf, bihb, bhhb, W1w, Vw, f1w,
                                        wbf0, wbf1r, wihbf, whhbf, lbias, W1bf, Vbf, f1bf);
  k_conv0m<<<dim3(BB, 4), 256, 0, stream>>>(x, wbf0, c0b, g0, be0, m0, v0, pbf);
  k_conv1m<<<dim3(BB, 4), 256, 0, stream>>>(pbf, wbf1r, c1b, g1, be1, m1, v1, x2bf);
  k_lstm_m<<<dim3(BB / 16, 2), 256, 0, stream>>>(x2bf, wihbf, whhbf, lbias, vbf, hT);
  k_q2<<<dim3(BB), 128, 0, stream>>>(hT, W2w, W2b, q2);
  k_score_m<<<dim3(BB, 4), 256, 0, stream>>>(vbf, W1bf, W1b, q2, Vbf, Vb, scoreT, pmax, psum);
  k_ctx_m<<<dim3(BB), 256, 0, stream>>>(vbf, scoreT, pmax, psum, ctxbf);
  k_heads_m<<<dim3(NTF, 4), 256, 0, stream>>>(ctxbf, f1bf, f1b, f2w, f2b, out);
}